// Round 16
// baseline (1149.940 us; speedup 1.0000x reference)
//
#include <hip/hip_runtime.h>
#include <hip/hip_fp16.h>

// CAPTNet block. B=8, CIN=3, H=W=256, DIM=48, HEADS=4 (ch=12), HID=96.
// Round 16: kA6 -> kA7. Differential evidence r10(clean) vs r13-15(dirty,
// ~400MB scratch writes): the fdot2-based conv is the prime suspect (only
// novel piece present in all dirty variants). kA7 reverts the conv to the
// r10/r12 plain-FMA fp32-weight form (1px, acc[24], proven clean + proven
// numerics), adds sched_barrier(0) between the two per-pixel calls, keeps
// r15's analytic-LN staging (halved FETCH, validated) and th in LDS.
// dwconv weights fp16 ch-pairs (r11/r12-proven) to fit 80KB LDS.
// k3/k4a/k5b verbatim r15 (passing, absmax 4.88e-4).
// region layout (r7): (b*256+gy)*98304 + chunk*4096 + gx*16, 24 chunks.
//   chunks 18..23: vdw fp16 (kA7 -> k4a); k4a writes y fp16 chunks 0..23.
// s0 (3 fp32) separate float4/pixel array (k4a -> k5b).

#define NPIX 65536
#define ROWB 98304        // bytes per (batch,row): 24 chunks * 4096
#define REGPB 25165824ull // bytes per batch in region
#define HSTRIDE 332       // k4a/k5b halo LDS row stride (half2 elems) [r7]
#define HA 324            // kA7 halo LDS row stride (u32/half2 elems)
#define KQ 258            // kA7 q/k fp16 LDS row stride (u32)

union F4U { float4 f4; unsigned int u[4]; };

__device__ __forceinline__ float2 uh2f(unsigned int u) {
  __half2 h; *(unsigned int*)&h = u; return __half22float2(h);
}
__device__ __forceinline__ unsigned int fpack(float a, float b) {
  __half2 h = __halves2half2(__float2half_rn(a), __float2half_rn(b));
  return *(unsigned int*)&h;
}

// ====== kA7: in_proj+LN1(analytic)+qkv conv(fp32 FMA)+dwconv+Gram+v ======
__global__ __launch_bounds__(256, 2) void kA7(
    const float* __restrict__ x, const float* __restrict__ ipw,
    const float* __restrict__ ipb, const float* __restrict__ lnw,
    const float* __restrict__ lnb, const float* __restrict__ qw,
    const float* __restrict__ qb, const float* __restrict__ dww,
    const float* __restrict__ dwb, char* __restrict__ region,
    float* __restrict__ red) {
  __shared__ unsigned int th[24 * HA];          // LN1 out, ch pairs fp16
  __shared__ unsigned int um[12 * HA];          // conv out 24ch fp16 pairs
  __shared__ unsigned int qsm[12 * KQ];         // q dwconv fp16 pairs (center)
  __shared__ unsigned int ksm[12 * KQ];         // k dwconv fp16 pairs
  __shared__ __align__(16) float wg[48 * 24];   // conv w fp32 [c][o]
  __shared__ float qbf[24];
  __shared__ unsigned int dwp[72 * 9];          // dw w fp16 ch-pairs
  __shared__ unsigned int dbp[72];
  __shared__ float s_ipw[144], s_ipb[48], s_lnw[48], s_lnb[48];
  __shared__ float s_C[14];   // LN1 analytic scalars
  const int tid = threadIdx.x;
  for (int i = tid; i < 648; i += 256)
    dwp[i] = fpack(dww[(i / 9) * 18 + (i % 9)], dww[(i / 9) * 18 + 9 + (i % 9)]);
  if (tid < 72) dbp[tid] = fpack(dwb[2 * tid], dwb[2 * tid + 1]);
  if (tid < 144) s_ipw[tid] = ipw[tid];
  if (tid < 48) { s_ipb[tid] = ipb[tid]; s_lnw[tid] = lnw[tid]; s_lnb[tid] = lnb[tid]; }
  // 14 analytic-LN scalars (validated r15):
  if (tid >= 192 && tid < 206) {
    const int e = tid - 192;
    float s = 0.f;
    if (e < 3) {
      for (int c = 0; c < 48; ++c) s += ipw[3 * c + e];
    } else if (e == 3) {
      for (int c = 0; c < 48; ++c) s += ipb[c];
    } else if (e < 10) {
      const int k0[6] = {0, 0, 0, 1, 1, 2}, k1[6] = {0, 1, 2, 1, 2, 2};
      const int a = k0[e - 4], bq = k1[e - 4];
      for (int c = 0; c < 48; ++c) s += ipw[3 * c + a] * ipw[3 * c + bq];
    } else if (e < 13) {
      for (int c = 0; c < 48; ++c) s += ipw[3 * c + (e - 10)] * ipb[c];
    } else {
      for (int c = 0; c < 48; ++c) s += ipb[c] * ipb[c];
    }
    s_C[e] = s;
  }
  const int b = blockIdx.x >> 8;
  const int tile = blockIdx.x & 255;
  const int ty0 = (tile >> 4) << 4, tx0 = (tile & 15) << 4;
  const int py = tid >> 4, px = tid & 15;
  const int hp = (py + 1) * 18 + (px + 1);
  char* regb = region + (size_t)b * REGPB;
  const int offs[9] = {-19, -18, -17, -1, 0, 1, 17, 18, 19};
  __syncthreads();

  auto stage_px = [&](int p) {   // p < 324 guaranteed by caller
    const int hy = p / 18, hx = p - hy * 18;
    const int gy = ty0 + hy - 1, gx = tx0 + hx - 1;
    const bool ok = ((unsigned)gy < 256u) && ((unsigned)gx < 256u);
    const int gn = (gy << 8) + gx;
    float x0 = 0.f, x1 = 0.f, x2 = 0.f;
    if (ok) {
      x0 = x[((size_t)b * 3 + 0) * NPIX + gn];
      x1 = x[((size_t)b * 3 + 1) * NPIX + gn];
      x2 = x[((size_t)b * 3 + 2) * NPIX + gn];
    }
    const float mu = (s_C[0]*x0 + s_C[1]*x1 + s_C[2]*x2 + s_C[3]) * (1.f/48.f);
    const float sumsq = s_C[4]*x0*x0 + s_C[7]*x1*x1 + s_C[9]*x2*x2
                      + 2.f*(s_C[5]*x0*x1 + s_C[6]*x0*x2 + s_C[8]*x1*x2
                             + s_C[10]*x0 + s_C[11]*x1 + s_C[12]*x2)
                      + s_C[13];
    const float var = sumsq * (1.f/48.f) - mu * mu;
    const float rs = rsqrtf(var + 1e-6f);
#pragma unroll
    for (int c2 = 0; c2 < 24; ++c2) {
      const float na = s_ipw[6*c2+0]*x0 + s_ipw[6*c2+1]*x1 + s_ipw[6*c2+2]*x2 + s_ipb[2*c2];
      const float nb = s_ipw[6*c2+3]*x0 + s_ipw[6*c2+4]*x1 + s_ipw[6*c2+5]*x2 + s_ipb[2*c2+1];
      th[c2 * HA + p] = fpack((na - mu) * rs * s_lnw[2*c2]   + s_lnb[2*c2],
                              (nb - mu) * rs * s_lnw[2*c2+1] + s_lnb[2*c2+1]);
    }
  };
  stage_px(tid);
  __builtin_amdgcn_sched_barrier(0);
  if (tid < 68) stage_px(tid + 256);
  __syncthreads();

  auto loadwg = [&](int cb) {   // conv weights fp32: wg[c*24+o] = qw[cb+o][c]
    for (int i = tid; i < 1152; i += 256) {
      const int c = i / 24, o = i - (i / 24) * 24;
      wg[c * 24 + o] = qw[(cb + o) * 48 + c];
    }
    if (tid < 24) qbf[tid] = qb[cb + tid];
  };
  auto conv_px = [&](int p) {   // conv 48->24 via fp32 FMA at one pixel (r10 form)
    const int hy = p / 18, hx = p - hy * 18;
    const int gy = ty0 + hy - 1, gx = tx0 + hx - 1;
    const bool ok = ((unsigned)gy < 256u) && ((unsigned)gx < 256u);
    float a[24];
#pragma unroll
    for (int j = 0; j < 24; ++j) a[j] = qbf[j];
#pragma unroll 4
    for (int c2 = 0; c2 < 24; ++c2) {
      const float2 t = uh2f(th[c2 * HA + p]);
      const float* w0 = &wg[(2 * c2) * 24];
      const float* w1 = &wg[(2 * c2 + 1) * 24];
#pragma unroll
      for (int o4 = 0; o4 < 6; ++o4) {
        const float4 wa = *(const float4*)&w0[4 * o4];
        const float4 wb = *(const float4*)&w1[4 * o4];
        a[4*o4+0] += wa.x * t.x + wb.x * t.y;
        a[4*o4+1] += wa.y * t.x + wb.y * t.y;
        a[4*o4+2] += wa.z * t.x + wb.z * t.y;
        a[4*o4+3] += wa.w * t.x + wb.w * t.y;
      }
    }
#pragma unroll
    for (int j = 0; j < 12; ++j)
      um[j * HA + p] = ok ? fpack(a[2 * j], a[2 * j + 1]) : 0u;
  };
  auto convPhase = [&]() {
    conv_px(tid);
    __builtin_amdgcn_sched_barrier(0);
    if (tid < 68) conv_px(tid + 256);
  };
  auto dwqk = [&](int cpb, unsigned int* dst) {   // dwconv 24ch (12 pairs)
#pragma unroll
    for (int j = 0; j < 12; ++j) {
      const float2 db = uh2f(dbp[cpb + j]);
      float a = db.x, bb = db.y;
      const unsigned int* hrow = &um[j * HA + hp];
      const unsigned int* wp = &dwp[(cpb + j) * 9];
#pragma unroll
      for (int t = 0; t < 9; ++t) {
        const float2 f = uh2f(hrow[offs[t]]);
        const float2 w = uh2f(wp[t]);
        a += w.x * f.x; bb += w.y * f.y;
      }
      dst[j * KQ + tid] = fpack(a, bb);
    }
  };
  auto dwv = [&](int cpb, int chunk0) {   // dwconv v 24ch -> fp16 chunks
    unsigned int vp[12];
#pragma unroll
    for (int j = 0; j < 12; ++j) {
      const float2 db = uh2f(dbp[cpb + j]);
      float a = db.x, bb = db.y;
      const unsigned int* hrow = &um[j * HA + hp];
      const unsigned int* wp = &dwp[(cpb + j) * 9];
#pragma unroll
      for (int t = 0; t < 9; ++t) {
        const float2 f = uh2f(hrow[offs[t]]);
        const float2 w = uh2f(wp[t]);
        a += w.x * f.x; bb += w.y * f.y;
      }
      vp[j] = fpack(a, bb);
    }
    char* vrow = regb + (size_t)(ty0 + py) * ROWB + ((tx0 + px) << 4);
#pragma unroll
    for (int q = 0; q < 3; ++q) {
      F4U u;
      u.u[0] = vp[4 * q]; u.u[1] = vp[4 * q + 1];
      u.u[2] = vp[4 * q + 2]; u.u[3] = vp[4 * q + 3];
      *(float4*)(vrow + (chunk0 + q) * 4096) = u.f4;
    }
  };
  auto gram2 = [&](int hbase) {   // 2 heads from fp16 qsm/ksm [r7 verbatim]
    for (int e = tid; e < 336; e += 256) {
      const int hh = e / 168, r2 = e - hh * 168;
      float s = 0.f;
      if (r2 < 144) {
        const int c = r2 / 12, d = r2 - (r2 / 12) * 12;
        const int qc = 12 * hh + c, kd = 12 * hh + d;
        const unsigned int* qr = &qsm[(qc >> 1) * KQ];
        const unsigned int* kr = &ksm[(kd >> 1) * KQ];
        const int q1 = qc & 1, k1 = kd & 1;
        for (int p = 0; p < 256; ++p) {
          const float2 fq = uh2f(qr[p]); const float2 fk = uh2f(kr[p]);
          s += (q1 ? fq.y : fq.x) * (k1 ? fk.y : fk.x);
        }
      } else if (r2 < 156) {
        const int qc = 12 * hh + (r2 - 144);
        const unsigned int* qr = &qsm[(qc >> 1) * KQ];
        const int q1 = qc & 1;
        for (int p = 0; p < 256; ++p) {
          const float2 fq = uh2f(qr[p]);
          const float v = q1 ? fq.y : fq.x;
          s += v * v;
        }
      } else {
        const int kd = 12 * hh + (r2 - 156);
        const unsigned int* kr = &ksm[(kd >> 1) * KQ];
        const int k1 = kd & 1;
        for (int p = 0; p < 256; ++p) {
          const float2 fk = uh2f(kr[p]);
          const float v = k1 ? fk.y : fk.x;
          s += v * v;
        }
      }
      atomicAdd(&red[b * 672 + (hbase + hh) * 168 + r2], s);
    }
  };

  loadwg(0);   __syncthreads(); convPhase(); __syncthreads(); dwqk(0, qsm);
  loadwg(48);  __syncthreads(); convPhase(); __syncthreads(); dwqk(24, ksm);
  __syncthreads(); gram2(0);
  loadwg(24);  __syncthreads(); convPhase(); __syncthreads(); dwqk(12, qsm);
  loadwg(72);  __syncthreads(); convPhase(); __syncthreads(); dwqk(36, ksm);
  __syncthreads(); gram2(2);
  loadwg(96);  __syncthreads(); convPhase(); __syncthreads(); dwv(48, 18);
  loadwg(120); __syncthreads(); convPhase(); __syncthreads(); dwv(60, 21);
}

// ================= k3: finalize attn, build fused M [r15 verbatim] ==========
__global__ __launch_bounds__(256) void k3_attn(const float* __restrict__ red,
                                               const float* __restrict__ temp,
                                               const float* __restrict__ aow,
                                               float* __restrict__ Mws) {
  __shared__ float attn[4 * 144];
  const int b = blockIdx.x, tid = threadIdx.x;
  const float* rb = red + b * 672;
  for (int e = tid; e < 576; e += 256) {
    const int h = e / 144, r = e - h * 144;
    const int c = r / 12, d = r - c * 12;
    const float g = rb[h * 168 + r];
    const float nq = fmaxf(sqrtf(rb[h * 168 + 144 + c]), 1e-12f);
    const float nk = fmaxf(sqrtf(rb[h * 168 + 156 + d]), 1e-12f);
    attn[e] = g / (nq * nk) * temp[h];
  }
  __syncthreads();
  if (tid < 48) {
    const int h = tid / 12, c = tid - h * 12;
    float* row = &attn[h * 144 + c * 12];
    float m = row[0];
    for (int d = 1; d < 12; ++d) m = fmaxf(m, row[d]);
    float s = 0.f;
    for (int d = 0; d < 12; ++d) { const float e2 = expf(row[d] - m); row[d] = e2; s += e2; }
    const float inv = 1.f / s;
    for (int d = 0; d < 12; ++d) row[d] *= inv;
  }
  __syncthreads();
  for (int e = tid; e < 2304; e += 256) {
    const int o = e / 48, j = e - o * 48;
    const int h = j / 12, d = j - h * 12;
    float s = 0.f;
    for (int c = 0; c < 12; ++c)
      s += aow[o * 48 + h * 12 + c] * attn[h * 144 + c * 12 + d];
    Mws[b * 2304 + e] = s;
  }
}

// ========== k4a: recompute in_proj, attn-out, LN2, ffn_in [r15 verbatim] ====
__global__ __launch_bounds__(256, 3) void k4a(
    char* __restrict__ region, float4* __restrict__ s0arr,
    const float* __restrict__ x, const float* __restrict__ ipw,
    const float* __restrict__ ipb, const float* __restrict__ Mws,
    const float* __restrict__ aob, const float* __restrict__ lnw,
    const float* __restrict__ lnb, const float* __restrict__ fiw,
    const float* __restrict__ fib, const float* __restrict__ opw) {
  __shared__ __align__(16) float MT[48 * 48];     // MT[j][o]
  __shared__ __align__(16) float wT2[48 * 192];   // wT2[c][pos], pos interleaved
  __shared__ float s_aob[48], s_lnw[48], s_lnb[48], s_fib2[192], s_opw[144];
  __shared__ float s_ipw[144], s_ipb[48];
  const int tid = threadIdx.x;
  const int b = blockIdx.x >> 8;
  const int gy = blockIdx.x & 255;
  const int n = (gy << 8) + tid;
  for (int i = tid; i < 2304; i += 256) {
    const int o = i / 48, j = i - o * 48;
    MT[j * 48 + o] = Mws[b * 2304 + i];
  }
  for (int i = tid; i < 9216; i += 256) {
    const int c = i / 192, pos = i - c * 192;
    const int ch = (pos & 1) ? 96 + (pos >> 1) : (pos >> 1);
    wT2[i] = fiw[ch * 48 + c];
  }
  if (tid < 192) {
    const int ch = (tid & 1) ? 96 + (tid >> 1) : (tid >> 1);
    s_fib2[tid] = fib[ch];
  }
  if (tid < 144) { s_opw[tid] = opw[tid]; s_ipw[tid] = ipw[tid]; }
  if (tid < 48) {
    s_aob[tid] = aob[tid]; s_lnw[tid] = lnw[tid]; s_lnb[tid] = lnb[tid];
    s_ipb[tid] = ipb[tid];
  }
  __syncthreads();
  char* rowp = region + (size_t)((b << 8) + gy) * ROWB + (tid << 4);
  float vv[48];
#pragma unroll
  for (int q = 0; q < 6; ++q) {
    F4U u; u.f4 = *(const float4*)(rowp + (18 + q) * 4096);
#pragma unroll
    for (int j = 0; j < 4; ++j) {
      const float2 f = uh2f(u.u[j]);
      vv[8 * q + 2 * j] = f.x; vv[8 * q + 2 * j + 1] = f.y;
    }
  }
  float y[48];
#pragma unroll
  for (int o = 0; o < 48; ++o) y[o] = s_aob[o];
#pragma unroll 4
  for (int j = 0; j < 48; ++j) {
    const float vj = vv[j];
    const float* mr = &MT[j * 48];
#pragma unroll
    for (int o4 = 0; o4 < 12; ++o4) {
      const float4 m = *(const float4*)&mr[o4 * 4];
      y[o4 * 4 + 0] += m.x * vj; y[o4 * 4 + 1] += m.y * vj;
      y[o4 * 4 + 2] += m.z * vj; y[o4 * 4 + 3] += m.w * vj;
    }
  }
  // recompute in_proj (xp) and add residual
  const float x0 = x[((size_t)b * 3 + 0) * NPIX + n];
  const float x1 = x[((size_t)b * 3 + 1) * NPIX + n];
  const float x2 = x[((size_t)b * 3 + 2) * NPIX + n];
  float mu = 0.f;
#pragma unroll
  for (int c = 0; c < 48; ++c) {
    y[c] += s_ipw[c * 3] * x0 + s_ipw[c * 3 + 1] * x1 + s_ipw[c * 3 + 2] * x2 + s_ipb[c];
    mu += y[c];
  }
  float s0 = 0.f, s1 = 0.f, s2 = 0.f;
#pragma unroll
  for (int c = 0; c < 48; ++c) {
    s0 += s_opw[c] * y[c]; s1 += s_opw[48 + c] * y[c]; s2 += s_opw[96 + c] * y[c];
  }
  float4 s0v; s0v.x = s0; s0v.y = s1; s0v.z = s2; s0v.w = 0.f;
  s0arr[(size_t)b * NPIX + n] = s0v;
  mu *= (1.f / 48.f);
  float var = 0.f;
#pragma unroll
  for (int c = 0; c < 48; ++c) { const float d = y[c] - mu; var += d * d; }
  const float rs2 = rsqrtf(var * (1.f / 48.f) + 1e-6f);
#pragma unroll
  for (int c = 0; c < 48; ++c) y[c] = (y[c] - mu) * rs2 * s_lnw[c] + s_lnb[c];
#pragma unroll
  for (int ob = 0; ob < 12; ++ob) {
    const int o0 = ob * 16;
    float acc[16];
#pragma unroll
    for (int j = 0; j < 16; ++j) acc[j] = s_fib2[o0 + j];
#pragma unroll 4
    for (int c = 0; c < 48; ++c) {
      const float xv = y[c];
      const float4 w0 = *(const float4*)&wT2[c * 192 + o0];
      const float4 w1 = *(const float4*)&wT2[c * 192 + o0 + 4];
      const float4 w2 = *(const float4*)&wT2[c * 192 + o0 + 8];
      const float4 w3 = *(const float4*)&wT2[c * 192 + o0 + 12];
      acc[0] += w0.x * xv; acc[1] += w0.y * xv; acc[2] += w0.z * xv; acc[3] += w0.w * xv;
      acc[4] += w1.x * xv; acc[5] += w1.y * xv; acc[6] += w1.z * xv; acc[7] += w1.w * xv;
      acc[8] += w2.x * xv; acc[9] += w2.y * xv; acc[10] += w2.z * xv; acc[11] += w2.w * xv;
      acc[12] += w3.x * xv; acc[13] += w3.y * xv; acc[14] += w3.z * xv; acc[15] += w3.w * xv;
    }
    F4U u;
    u.u[0] = fpack(acc[0], acc[1]);   u.u[1] = fpack(acc[2], acc[3]);
    u.u[2] = fpack(acc[4], acc[5]);   u.u[3] = fpack(acc[6], acc[7]);
    *(float4*)(rowp + (2 * ob) * 4096) = u.f4;
    u.u[0] = fpack(acc[8], acc[9]);   u.u[1] = fpack(acc[10], acc[11]);
    u.u[2] = fpack(acc[12], acc[13]); u.u[3] = fpack(acc[14], acc[15]);
    *(float4*)(rowp + (2 * ob + 1) * 4096) = u.f4;
  }
}

// ====== k5b: dw + SimpleGate + ffn_out + out_proj [r15 verbatim] ============
__global__ __launch_bounds__(256, 3) void k5b(
    const char* __restrict__ region, const float4* __restrict__ s0arr,
    const float* __restrict__ fdww, const float* __restrict__ fdwb,
    const float* __restrict__ fow, const float* __restrict__ fob,
    const float* __restrict__ opw, const float* __restrict__ opb,
    float* __restrict__ out) {
  __shared__ unsigned int halo[12 * HSTRIDE];
  __shared__ __align__(16) float fowT[96 * 48];   // fowT[c1][o] = fow[o][c1]
  __shared__ float s_dww2[1728], s_dwb2[192], s_opw[144], s_fob[48];
  const int tid = threadIdx.x;
  for (int i = tid; i < 4608; i += 256) {
    const int c = i / 48, o = i - c * 48;
    fowT[i] = fow[o * 96 + c];
  }
  for (int i = tid; i < 1728; i += 256) {
    const int P = i / 9, t = i - P * 9;
    const int ch = (P & 1) ? 96 + (P >> 1) : (P >> 1);
    s_dww2[i] = fdww[ch * 9 + t];
  }
  if (tid < 192) {
    const int ch = (tid & 1) ? 96 + (tid >> 1) : (tid >> 1);
    s_dwb2[tid] = fdwb[ch];
  }
  if (tid < 144) s_opw[tid] = opw[tid];
  if (tid < 48) s_fob[tid] = fob[tid];
  const int b = blockIdx.x >> 8;
  const int tile = blockIdx.x & 255;
  const int ty0 = (tile >> 4) << 4, tx0 = (tile & 15) << 4;
  const int py = tid >> 4, px = tid & 15;
  const int hp = (py + 1) * 18 + (px + 1);
  const int gn = ((ty0 + py) << 8) + (tx0 + px);
  const char* regb = region + (size_t)b * REGPB;

  float4 pf[4];
  auto prefetch = [&](int cb) {
#pragma unroll
    for (int r = 0; r < 4; ++r) {
      const int i = tid + (r << 8);
      float4 z = {0.f, 0.f, 0.f, 0.f}; pf[r] = z;
      if (i < 972) {
        const int c4 = i / 324, p = i - c4 * 324;
        const int hy = p / 18, hx = p - hy * 18;
        const int gy = ty0 + hy - 1, gx = tx0 + hx - 1;
        if (((unsigned)gy < 256u) && ((unsigned)gx < 256u))
          pf[r] = *(const float4*)(regb + (size_t)gy * ROWB + (cb + c4) * 4096 + (gx << 4));
      }
    }
  };
  auto commit = [&]() {
#pragma unroll
    for (int r = 0; r < 4; ++r) {
      const int i = tid + (r << 8);
      if (i < 972) {
        const int c4 = i / 324, p = i - c4 * 324;
        F4U u; u.f4 = pf[r];
        const int pb = c4 << 2;
#pragma unroll
        for (int j = 0; j < 4; ++j) halo[(pb + j) * HSTRIDE + p] = u.u[j];
      }
    }
  };

  float facc[48];
#pragma unroll
  for (int o = 0; o < 48; ++o) facc[o] = 0.f;
  prefetch(0);
  for (int s = 0; s < 8; ++s) {
    __syncthreads(); commit(); __syncthreads();
    if (s < 7) prefetch(3 * (s + 1));
    const int offs[9] = {-19, -18, -17, -1, 0, 1, 17, 18, 19};
#pragma unroll
    for (int pp = 0; pp < 12; ++pp) {
      const int P = 24 * s + 2 * pp;
      const float* w0 = &s_dww2[P * 9];
      const float* w1 = w0 + 9;
      const unsigned int* hrow = &halo[pp * HSTRIDE + hp];
      float a = s_dwb2[P], b2 = s_dwb2[P + 1];
#pragma unroll
      for (int t = 0; t < 9; ++t) {
        const float2 f = uh2f(hrow[offs[t]]);
        a += w0[t] * f.x; b2 += w1[t] * f.y;
      }
      const float gate = a * b2;
      const float* fr = &fowT[(12 * s + pp) * 48];
#pragma unroll
      for (int o4 = 0; o4 < 12; ++o4) {
        const float4 m = *(const float4*)&fr[o4 * 4];
        facc[o4 * 4 + 0] += m.x * gate; facc[o4 * 4 + 1] += m.y * gate;
        facc[o4 * 4 + 2] += m.z * gate; facc[o4 * 4 + 3] += m.w * gate;
      }
    }
  }
  const float4 s0v = s0arr[(size_t)b * NPIX + gn];
  float r0 = s0v.x + opb[0];
  float r1 = s0v.y + opb[1];
  float r2 = s0v.z + opb[2];
#pragma unroll
  for (int o = 0; o < 48; ++o) {
    const float f = facc[o] + s_fob[o];
    r0 += s_opw[o] * f; r1 += s_opw[48 + o] * f; r2 += s_opw[96 + o] * f;
  }
  out[((size_t)b * 3 + 0) * NPIX + gn] = r0;
  out[((size_t)b * 3 + 1) * NPIX + gn] = r1;
  out[((size_t)b * 3 + 2) * NPIX + gn] = r2;
}

extern "C" void kernel_launch(void* const* d_in, const int* in_sizes, int n_in,
                              void* d_out, int out_size, void* d_ws, size_t ws_size,
                              hipStream_t stream) {
  const float* x    = (const float*)d_in[0];
  const float* ipw  = (const float*)d_in[1];
  const float* ipb  = (const float*)d_in[2];
  const float* ln1w = (const float*)d_in[3];
  const float* ln1b = (const float*)d_in[4];
  const float* qw   = (const float*)d_in[5];
  const float* qb   = (const float*)d_in[6];
  const float* qdww = (const float*)d_in[7];
  const float* qdwb = (const float*)d_in[8];
  const float* temp = (const float*)d_in[9];
  const float* aow  = (const float*)d_in[10];
  const float* aob  = (const float*)d_in[11];
  const float* ln2w = (const float*)d_in[12];
  const float* ln2b = (const float*)d_in[13];
  const float* fiw  = (const float*)d_in[14];
  const float* fib  = (const float*)d_in[15];
  const float* fdww = (const float*)d_in[16];
  const float* fdwb = (const float*)d_in[17];
  const float* fow  = (const float*)d_in[18];
  const float* fob  = (const float*)d_in[19];
  const float* opw  = (const float*)d_in[20];
  const float* opb  = (const float*)d_in[21];

  const size_t s0Per = (size_t)NPIX * 16;
  int bc = 8;
  while (bc > 1 &&
         (size_t)bc * (REGPB + s0Per) + (5376 + 18432) * 4 > ws_size)
    bc >>= 1;
  char* region = (char*)d_ws;
  float4* s0arr = (float4*)(region + (size_t)bc * REGPB);
  float* red = (float*)((char*)s0arr + (size_t)bc * s0Per);
  float* Mws = red + 5376;
  hipMemsetAsync(red, 0, 5376 * sizeof(float), stream);
  for (int b0 = 0; b0 < 8; b0 += bc) {
    kA7<<<bc * 256, 256, 0, stream>>>(x + (size_t)b0 * 3 * NPIX, ipw, ipb,
                                      ln1w, ln1b, qw, qb, qdww, qdwb,
                                      region, red + b0 * 672);
    k3_attn<<<bc, 256, 0, stream>>>(red + b0 * 672, temp, aow,
                                    Mws + (size_t)b0 * 2304);
    k4a<<<bc * 256, 256, 0, stream>>>(region, s0arr, x + (size_t)b0 * 3 * NPIX,
                                      ipw, ipb, Mws + (size_t)b0 * 2304, aob,
                                      ln2w, ln2b, fiw, fib, opw);
    k5b<<<bc * 256, 256, 0, stream>>>(region, s0arr, fdww, fdwb, fow, fob,
                                      opw, opb,
                                      (float*)d_out + (size_t)b0 * 3 * NPIX);
  }
}

// Round 18
// 975.731 us; speedup vs baseline: 1.1785x; 1.1785x over previous
//
#include <hip/hip_runtime.h>
#include <hip/hip_fp16.h>

// CAPTNet block. B=8, CIN=3, H=W=256, DIM=48, HEADS=4 (ch=12), HID=96.
// Round 18: round 17 with the kA4 dwconv call-site bug fixed. r17 pasted
// kA7's PAIR-unit dwqk/dwv args (0/24/12/36, 48/60) onto kA4's FULL-CHANNEL
// unit body (s_dwb[cb+2j], s_dww[(cb+2j)*9]) -> k/v dwconv used wrong
// channels' weights (absmax 1.3e-2). Correct args (r13): 0/48/24/72, 96/120.
// The intended r17 experiment stands: k4a/k5b launch_bounds (256,3)->(256,2)
// to eliminate their spill (r7 counters: k4a 961MB vs 260 logical at VGPR=68;
// live set ~112 regs fits under 128).
// region layout (r7): (b*256+gy)*98304 + chunk*4096 + gx*16, 24 chunks.
//   chunks 18..23: vdw fp16 (kA4 -> k4a); k4a writes y fp16 chunks 0..23.
// s0 (3 fp32) separate float4/pixel array (k4a -> k5b).

#define NPIX 65536
#define ROWB 98304        // bytes per (batch,row): 24 chunks * 4096
#define REGPB 25165824ull // bytes per batch in region
#define HSTRIDE 332       // k4a/k5b halo LDS row stride (half2 elems) [r7]
#define HA 324            // kA4 halo LDS row stride (u32/half2 elems)
#define KQ 258            // kA4 q/k fp16 LDS row stride (u32)

union F4U { float4 f4; unsigned int u[4]; };

typedef _Float16 h2f __attribute__((ext_vector_type(2)));
union U32H2 { unsigned int u; h2f h; };

__device__ __forceinline__ float2 uh2f(unsigned int u) {
  __half2 h; *(unsigned int*)&h = u; return __half22float2(h);
}
__device__ __forceinline__ unsigned int fpack(float a, float b) {
  __half2 h = __halves2half2(__float2half_rn(a), __float2half_rn(b));
  return *(unsigned int*)&h;
}
__device__ __forceinline__ float fdot2u(unsigned int a, unsigned int b, float c) {
  U32H2 ua, ub; ua.u = a; ub.u = b;
  return __builtin_amdgcn_fdot2(ua.h, ub.h, c, false);
}

// ================= kA4: in_proj+LN1+qkv conv(dot2)+dwconv+Gram+v ==========
__global__ __launch_bounds__(256, 2) void kA4(
    const float* __restrict__ x, const float* __restrict__ ipw,
    const float* __restrict__ ipb, const float* __restrict__ lnw,
    const float* __restrict__ lnb, const float* __restrict__ qw,
    const float* __restrict__ qb, const float* __restrict__ dww,
    const float* __restrict__ dwb, char* __restrict__ region,
    float* __restrict__ red) {
  __shared__ unsigned int th[24 * HA];          // LN1 out, ch pairs fp16
  __shared__ unsigned int um[12 * HA];          // conv out 24ch fp16 pairs
  __shared__ unsigned int qsm[12 * KQ];         // q dwconv fp16 pairs (center)
  __shared__ unsigned int ksm[12 * KQ];         // k dwconv fp16 pairs
  __shared__ __align__(16) unsigned int wgp[576];  // conv w fp16 pairs [c2][o]
  __shared__ float qbf[24];
  __shared__ float s_dww[1296], s_dwb[144];
  __shared__ float s_ipw[144], s_ipb[48], s_lnw[48], s_lnb[48];
  const int tid = threadIdx.x;
  for (int i = tid; i < 1296; i += 256) s_dww[i] = dww[i];
  if (tid < 144) { s_dwb[tid] = dwb[tid]; s_ipw[tid] = ipw[tid]; }
  if (tid < 48) { s_ipb[tid] = ipb[tid]; s_lnw[tid] = lnw[tid]; s_lnb[tid] = lnb[tid]; }
  const int b = blockIdx.x >> 8;
  const int tile = blockIdx.x & 255;
  const int ty0 = (tile >> 4) << 4, tx0 = (tile & 15) << 4;
  const int py = tid >> 4, px = tid & 15;
  const int hp = (py + 1) * 18 + (px + 1);
  char* regb = region + (size_t)b * REGPB;
  const int offs[9] = {-19, -18, -17, -1, 0, 1, 17, 18, 19};

  const int p0 = tid, p1 = tid + 256;
  const bool has1 = (p1 < 324);
  bool okA[2];
  __syncthreads();   // params visible before th staging uses them

  // stage th = LN1(in_proj(x)) at all 324 halo px (fp16 pairs in LDS)
  for (int r = 0; r < 2; ++r) {
    const int p = r ? p1 : p0;
    if (p >= 324) break;
    const int hy = p / 18, hx = p - hy * 18;
    const int gy = ty0 + hy - 1, gx = tx0 + hx - 1;
    const bool ok = ((unsigned)gy < 256u) && ((unsigned)gx < 256u);
    okA[r] = ok;
    const int gn = (gy << 8) + gx;
    float x0 = 0.f, x1 = 0.f, x2 = 0.f;
    if (ok) {
      x0 = x[((size_t)b * 3 + 0) * NPIX + gn];
      x1 = x[((size_t)b * 3 + 1) * NPIX + gn];
      x2 = x[((size_t)b * 3 + 2) * NPIX + gn];
    }
    float xn[48]; float mu = 0.f;
#pragma unroll
    for (int c = 0; c < 48; ++c) {
      xn[c] = s_ipw[3*c]*x0 + s_ipw[3*c+1]*x1 + s_ipw[3*c+2]*x2 + s_ipb[c];
      mu += xn[c];
    }
    mu *= (1.f / 48.f);
    float var = 0.f;
#pragma unroll
    for (int c = 0; c < 48; ++c) { const float d = xn[c] - mu; var += d * d; }
    const float rs = rsqrtf(var * (1.f / 48.f) + 1e-6f);
#pragma unroll
    for (int c2 = 0; c2 < 24; ++c2)
      th[c2 * HA + p] = fpack((xn[2*c2]   - mu) * rs * s_lnw[2*c2]   + s_lnb[2*c2],
                              (xn[2*c2+1] - mu) * rs * s_lnw[2*c2+1] + s_lnb[2*c2+1]);
  }
  const bool ok0 = okA[0];
  const bool ok1 = has1 && okA[1];
  __syncthreads();

  auto loadwg = [&](int cb) {   // pack conv weights: wgp[c2*24+o]=(w[o][2c2],w[o][2c2+1])
    for (int i = tid; i < 576; i += 256) {
      const int c2 = i / 24, o = i - c2 * 24;
      wgp[i] = fpack(qw[(cb + o) * 48 + 2 * c2], qw[(cb + o) * 48 + 2 * c2 + 1]);
    }
    if (tid < 24) qbf[tid] = qb[cb + tid];
  };
  auto convPhase = [&]() {   // conv 48->24 via dot2; both px share weight reads
    float a0[24], a1[24];
#pragma unroll
    for (int j = 0; j < 24; ++j) { a0[j] = qbf[j]; a1[j] = qbf[j]; }
#pragma unroll 4
    for (int c2 = 0; c2 < 24; ++c2) {
      const unsigned int t0 = th[c2 * HA + p0];
      const unsigned int t1 = has1 ? th[c2 * HA + p1] : 0u;
      const uint4* wr = (const uint4*)&wgp[c2 * 24];
#pragma unroll
      for (int k = 0; k < 6; ++k) {
        const uint4 w = wr[k];
        a0[4*k+0] = fdot2u(t0, w.x, a0[4*k+0]);
        a0[4*k+1] = fdot2u(t0, w.y, a0[4*k+1]);
        a0[4*k+2] = fdot2u(t0, w.z, a0[4*k+2]);
        a0[4*k+3] = fdot2u(t0, w.w, a0[4*k+3]);
        a1[4*k+0] = fdot2u(t1, w.x, a1[4*k+0]);
        a1[4*k+1] = fdot2u(t1, w.y, a1[4*k+1]);
        a1[4*k+2] = fdot2u(t1, w.z, a1[4*k+2]);
        a1[4*k+3] = fdot2u(t1, w.w, a1[4*k+3]);
      }
    }
#pragma unroll
    for (int j = 0; j < 12; ++j)
      um[j * HA + p0] = ok0 ? fpack(a0[2 * j], a0[2 * j + 1]) : 0u;
    if (has1) {
#pragma unroll
      for (int j = 0; j < 12; ++j)
        um[j * HA + p1] = ok1 ? fpack(a1[2 * j], a1[2 * j + 1]) : 0u;
    }
  };
  auto dwqk = [&](int cb, unsigned int* dst) {   // dwconv 24ch, cb = FULL ch base
#pragma unroll
    for (int j = 0; j < 12; ++j) {
      float a = s_dwb[cb + 2 * j], bb = s_dwb[cb + 2 * j + 1];
      const unsigned int* hrow = &um[j * HA + hp];
      const float* w0 = &s_dww[(cb + 2 * j) * 9];
      const float* w1 = w0 + 9;
#pragma unroll
      for (int t = 0; t < 9; ++t) {
        const float2 f = uh2f(hrow[offs[t]]);
        a += w0[t] * f.x; bb += w1[t] * f.y;
      }
      dst[j * KQ + tid] = fpack(a, bb);
    }
  };
  auto dwv = [&](int cb, int chunk0) {   // dwconv v 24ch, cb = FULL ch base
    unsigned int vp[12];
#pragma unroll
    for (int j = 0; j < 12; ++j) {
      float a = s_dwb[cb + 2 * j], bb = s_dwb[cb + 2 * j + 1];
      const unsigned int* hrow = &um[j * HA + hp];
      const float* w0 = &s_dww[(cb + 2 * j) * 9];
      const float* w1 = w0 + 9;
#pragma unroll
      for (int t = 0; t < 9; ++t) {
        const float2 f = uh2f(hrow[offs[t]]);
        a += w0[t] * f.x; bb += w1[t] * f.y;
      }
      vp[j] = fpack(a, bb);
    }
    char* vrow = regb + (size_t)(ty0 + py) * ROWB + ((tx0 + px) << 4);
#pragma unroll
    for (int q = 0; q < 3; ++q) {
      F4U u;
      u.u[0] = vp[4 * q]; u.u[1] = vp[4 * q + 1];
      u.u[2] = vp[4 * q + 2]; u.u[3] = vp[4 * q + 3];
      *(float4*)(vrow + (chunk0 + q) * 4096) = u.f4;
    }
  };
  auto gram2 = [&](int hbase) {   // 2 heads from fp16 qsm/ksm [r7 verbatim]
    for (int e = tid; e < 336; e += 256) {
      const int hh = e / 168, r2 = e - hh * 168;
      float s = 0.f;
      if (r2 < 144) {
        const int c = r2 / 12, d = r2 - (r2 / 12) * 12;
        const int qc = 12 * hh + c, kd = 12 * hh + d;
        const unsigned int* qr = &qsm[(qc >> 1) * KQ];
        const unsigned int* kr = &ksm[(kd >> 1) * KQ];
        const int q1 = qc & 1, k1 = kd & 1;
        for (int p = 0; p < 256; ++p) {
          const float2 fq = uh2f(qr[p]); const float2 fk = uh2f(kr[p]);
          s += (q1 ? fq.y : fq.x) * (k1 ? fk.y : fk.x);
        }
      } else if (r2 < 156) {
        const int qc = 12 * hh + (r2 - 144);
        const unsigned int* qr = &qsm[(qc >> 1) * KQ];
        const int q1 = qc & 1;
        for (int p = 0; p < 256; ++p) {
          const float2 fq = uh2f(qr[p]);
          const float v = q1 ? fq.y : fq.x;
          s += v * v;
        }
      } else {
        const int kd = 12 * hh + (r2 - 156);
        const unsigned int* kr = &ksm[(kd >> 1) * KQ];
        const int k1 = kd & 1;
        for (int p = 0; p < 256; ++p) {
          const float2 fk = uh2f(kr[p]);
          const float v = k1 ? fk.y : fk.x;
          s += v * v;
        }
      }
      atomicAdd(&red[b * 672 + (hbase + hh) * 168 + r2], s);
    }
  };

  loadwg(0);   __syncthreads(); convPhase(); __syncthreads(); dwqk(0, qsm);
  loadwg(48);  __syncthreads(); convPhase(); __syncthreads(); dwqk(48, ksm);
  __syncthreads(); gram2(0);
  loadwg(24);  __syncthreads(); convPhase(); __syncthreads(); dwqk(24, qsm);
  loadwg(72);  __syncthreads(); convPhase(); __syncthreads(); dwqk(72, ksm);
  __syncthreads(); gram2(2);
  loadwg(96);  __syncthreads(); convPhase(); __syncthreads(); dwv(96, 18);
  loadwg(120); __syncthreads(); convPhase(); __syncthreads(); dwv(120, 21);
}

// ================= k3: finalize attn, build fused M [r13 verbatim] ==========
__global__ __launch_bounds__(256) void k3_attn(const float* __restrict__ red,
                                               const float* __restrict__ temp,
                                               const float* __restrict__ aow,
                                               float* __restrict__ Mws) {
  __shared__ float attn[4 * 144];
  const int b = blockIdx.x, tid = threadIdx.x;
  const float* rb = red + b * 672;
  for (int e = tid; e < 576; e += 256) {
    const int h = e / 144, r = e - h * 144;
    const int c = r / 12, d = r - c * 12;
    const float g = rb[h * 168 + r];
    const float nq = fmaxf(sqrtf(rb[h * 168 + 144 + c]), 1e-12f);
    const float nk = fmaxf(sqrtf(rb[h * 168 + 156 + d]), 1e-12f);
    attn[e] = g / (nq * nk) * temp[h];
  }
  __syncthreads();
  if (tid < 48) {
    const int h = tid / 12, c = tid - h * 12;
    float* row = &attn[h * 144 + c * 12];
    float m = row[0];
    for (int d = 1; d < 12; ++d) m = fmaxf(m, row[d]);
    float s = 0.f;
    for (int d = 0; d < 12; ++d) { const float e2 = expf(row[d] - m); row[d] = e2; s += e2; }
    const float inv = 1.f / s;
    for (int d = 0; d < 12; ++d) row[d] *= inv;
  }
  __syncthreads();
  for (int e = tid; e < 2304; e += 256) {
    const int o = e / 48, j = e - o * 48;
    const int h = j / 12, d = j - h * 12;
    float s = 0.f;
    for (int c = 0; c < 12; ++c)
      s += aow[o * 48 + h * 12 + c] * attn[h * 144 + c * 12 + d];
    Mws[b * 2304 + e] = s;
  }
}

// ==== k4a: recompute in_proj, attn-out, LN2, ffn_in [(256,2): no spill] =====
__global__ __launch_bounds__(256, 2) void k4a(
    char* __restrict__ region, float4* __restrict__ s0arr,
    const float* __restrict__ x, const float* __restrict__ ipw,
    const float* __restrict__ ipb, const float* __restrict__ Mws,
    const float* __restrict__ aob, const float* __restrict__ lnw,
    const float* __restrict__ lnb, const float* __restrict__ fiw,
    const float* __restrict__ fib, const float* __restrict__ opw) {
  __shared__ __align__(16) float MT[48 * 48];     // MT[j][o]
  __shared__ __align__(16) float wT2[48 * 192];   // wT2[c][pos], pos interleaved
  __shared__ float s_aob[48], s_lnw[48], s_lnb[48], s_fib2[192], s_opw[144];
  __shared__ float s_ipw[144], s_ipb[48];
  const int tid = threadIdx.x;
  const int b = blockIdx.x >> 8;
  const int gy = blockIdx.x & 255;
  const int n = (gy << 8) + tid;
  for (int i = tid; i < 2304; i += 256) {
    const int o = i / 48, j = i - o * 48;
    MT[j * 48 + o] = Mws[b * 2304 + i];
  }
  for (int i = tid; i < 9216; i += 256) {
    const int c = i / 192, pos = i - c * 192;
    const int ch = (pos & 1) ? 96 + (pos >> 1) : (pos >> 1);
    wT2[i] = fiw[ch * 48 + c];
  }
  if (tid < 192) {
    const int ch = (tid & 1) ? 96 + (tid >> 1) : (tid >> 1);
    s_fib2[tid] = fib[ch];
  }
  if (tid < 144) { s_opw[tid] = opw[tid]; s_ipw[tid] = ipw[tid]; }
  if (tid < 48) {
    s_aob[tid] = aob[tid]; s_lnw[tid] = lnw[tid]; s_lnb[tid] = lnb[tid];
    s_ipb[tid] = ipb[tid];
  }
  __syncthreads();
  char* rowp = region + (size_t)((b << 8) + gy) * ROWB + (tid << 4);
  float vv[48];
#pragma unroll
  for (int q = 0; q < 6; ++q) {
    F4U u; u.f4 = *(const float4*)(rowp + (18 + q) * 4096);
#pragma unroll
    for (int j = 0; j < 4; ++j) {
      const float2 f = uh2f(u.u[j]);
      vv[8 * q + 2 * j] = f.x; vv[8 * q + 2 * j + 1] = f.y;
    }
  }
  float y[48];
#pragma unroll
  for (int o = 0; o < 48; ++o) y[o] = s_aob[o];
#pragma unroll 4
  for (int j = 0; j < 48; ++j) {
    const float vj = vv[j];
    const float* mr = &MT[j * 48];
#pragma unroll
    for (int o4 = 0; o4 < 12; ++o4) {
      const float4 m = *(const float4*)&mr[o4 * 4];
      y[o4 * 4 + 0] += m.x * vj; y[o4 * 4 + 1] += m.y * vj;
      y[o4 * 4 + 2] += m.z * vj; y[o4 * 4 + 3] += m.w * vj;
    }
  }
  // recompute in_proj (xp) and add residual
  const float x0 = x[((size_t)b * 3 + 0) * NPIX + n];
  const float x1 = x[((size_t)b * 3 + 1) * NPIX + n];
  const float x2 = x[((size_t)b * 3 + 2) * NPIX + n];
  float mu = 0.f;
#pragma unroll
  for (int c = 0; c < 48; ++c) {
    y[c] += s_ipw[c * 3] * x0 + s_ipw[c * 3 + 1] * x1 + s_ipw[c * 3 + 2] * x2 + s_ipb[c];
    mu += y[c];
  }
  float s0 = 0.f, s1 = 0.f, s2 = 0.f;
#pragma unroll
  for (int c = 0; c < 48; ++c) {
    s0 += s_opw[c] * y[c]; s1 += s_opw[48 + c] * y[c]; s2 += s_opw[96 + c] * y[c];
  }
  float4 s0v; s0v.x = s0; s0v.y = s1; s0v.z = s2; s0v.w = 0.f;
  s0arr[(size_t)b * NPIX + n] = s0v;
  mu *= (1.f / 48.f);
  float var = 0.f;
#pragma unroll
  for (int c = 0; c < 48; ++c) { const float d = y[c] - mu; var += d * d; }
  const float rs2 = rsqrtf(var * (1.f / 48.f) + 1e-6f);
#pragma unroll
  for (int c = 0; c < 48; ++c) y[c] = (y[c] - mu) * rs2 * s_lnw[c] + s_lnb[c];
#pragma unroll
  for (int ob = 0; ob < 12; ++ob) {
    const int o0 = ob * 16;
    float acc[16];
#pragma unroll
    for (int j = 0; j < 16; ++j) acc[j] = s_fib2[o0 + j];
#pragma unroll 4
    for (int c = 0; c < 48; ++c) {
      const float xv = y[c];
      const float4 w0 = *(const float4*)&wT2[c * 192 + o0];
      const float4 w1 = *(const float4*)&wT2[c * 192 + o0 + 4];
      const float4 w2 = *(const float4*)&wT2[c * 192 + o0 + 8];
      const float4 w3 = *(const float4*)&wT2[c * 192 + o0 + 12];
      acc[0] += w0.x * xv; acc[1] += w0.y * xv; acc[2] += w0.z * xv; acc[3] += w0.w * xv;
      acc[4] += w1.x * xv; acc[5] += w1.y * xv; acc[6] += w1.z * xv; acc[7] += w1.w * xv;
      acc[8] += w2.x * xv; acc[9] += w2.y * xv; acc[10] += w2.z * xv; acc[11] += w2.w * xv;
      acc[12] += w3.x * xv; acc[13] += w3.y * xv; acc[14] += w3.z * xv; acc[15] += w3.w * xv;
    }
    F4U u;
    u.u[0] = fpack(acc[0], acc[1]);   u.u[1] = fpack(acc[2], acc[3]);
    u.u[2] = fpack(acc[4], acc[5]);   u.u[3] = fpack(acc[6], acc[7]);
    *(float4*)(rowp + (2 * ob) * 4096) = u.f4;
    u.u[0] = fpack(acc[8], acc[9]);   u.u[1] = fpack(acc[10], acc[11]);
    u.u[2] = fpack(acc[12], acc[13]); u.u[3] = fpack(acc[14], acc[15]);
    *(float4*)(rowp + (2 * ob + 1) * 4096) = u.f4;
  }
}

// ====== k5b: dw + SimpleGate + ffn_out + out_proj [(256,2): no spill] =======
__global__ __launch_bounds__(256, 2) void k5b(
    const char* __restrict__ region, const float4* __restrict__ s0arr,
    const float* __restrict__ fdww, const float* __restrict__ fdwb,
    const float* __restrict__ fow, const float* __restrict__ fob,
    const float* __restrict__ opw, const float* __restrict__ opb,
    float* __restrict__ out) {
  __shared__ unsigned int halo[12 * HSTRIDE];
  __shared__ __align__(16) float fowT[96 * 48];   // fowT[c1][o] = fow[o][c1]
  __shared__ float s_dww2[1728], s_dwb2[192], s_opw[144], s_fob[48];
  const int tid = threadIdx.x;
  for (int i = tid; i < 4608; i += 256) {
    const int c = i / 48, o = i - c * 48;
    fowT[i] = fow[o * 96 + c];
  }
  for (int i = tid; i < 1728; i += 256) {
    const int P = i / 9, t = i - P * 9;
    const int ch = (P & 1) ? 96 + (P >> 1) : (P >> 1);
    s_dww2[i] = fdww[ch * 9 + t];
  }
  if (tid < 192) {
    const int ch = (tid & 1) ? 96 + (tid >> 1) : (tid >> 1);
    s_dwb2[tid] = fdwb[ch];
  }
  if (tid < 144) s_opw[tid] = opw[tid];
  if (tid < 48) s_fob[tid] = fob[tid];
  const int b = blockIdx.x >> 8;
  const int tile = blockIdx.x & 255;
  const int ty0 = (tile >> 4) << 4, tx0 = (tile & 15) << 4;
  const int py = tid >> 4, px = tid & 15;
  const int hp = (py + 1) * 18 + (px + 1);
  const int gn = ((ty0 + py) << 8) + (tx0 + px);
  const char* regb = region + (size_t)b * REGPB;

  float4 pf[4];
  auto prefetch = [&](int cb) {
#pragma unroll
    for (int r = 0; r < 4; ++r) {
      const int i = tid + (r << 8);
      float4 z = {0.f, 0.f, 0.f, 0.f}; pf[r] = z;
      if (i < 972) {
        const int c4 = i / 324, p = i - c4 * 324;
        const int hy = p / 18, hx = p - hy * 18;
        const int gy = ty0 + hy - 1, gx = tx0 + hx - 1;
        if (((unsigned)gy < 256u) && ((unsigned)gx < 256u))
          pf[r] = *(const float4*)(regb + (size_t)gy * ROWB + (cb + c4) * 4096 + (gx << 4));
      }
    }
  };
  auto commit = [&]() {
#pragma unroll
    for (int r = 0; r < 4; ++r) {
      const int i = tid + (r << 8);
      if (i < 972) {
        const int c4 = i / 324, p = i - c4 * 324;
        F4U u; u.f4 = pf[r];
        const int pb = c4 << 2;
#pragma unroll
        for (int j = 0; j < 4; ++j) halo[(pb + j) * HSTRIDE + p] = u.u[j];
      }
    }
  };

  float facc[48];
#pragma unroll
  for (int o = 0; o < 48; ++o) facc[o] = 0.f;
  prefetch(0);
  for (int s = 0; s < 8; ++s) {
    __syncthreads(); commit(); __syncthreads();
    if (s < 7) prefetch(3 * (s + 1));
    const int offs[9] = {-19, -18, -17, -1, 0, 1, 17, 18, 19};
#pragma unroll
    for (int pp = 0; pp < 12; ++pp) {
      const int P = 24 * s + 2 * pp;
      const float* w0 = &s_dww2[P * 9];
      const float* w1 = w0 + 9;
      const unsigned int* hrow = &halo[pp * HSTRIDE + hp];
      float a = s_dwb2[P], b2 = s_dwb2[P + 1];
#pragma unroll
      for (int t = 0; t < 9; ++t) {
        const float2 f = uh2f(hrow[offs[t]]);
        a += w0[t] * f.x; b2 += w1[t] * f.y;
      }
      const float gate = a * b2;
      const float* fr = &fowT[(12 * s + pp) * 48];
#pragma unroll
      for (int o4 = 0; o4 < 12; ++o4) {
        const float4 m = *(const float4*)&fr[o4 * 4];
        facc[o4 * 4 + 0] += m.x * gate; facc[o4 * 4 + 1] += m.y * gate;
        facc[o4 * 4 + 2] += m.z * gate; facc[o4 * 4 + 3] += m.w * gate;
      }
    }
  }
  const float4 s0v = s0arr[(size_t)b * NPIX + gn];
  float r0 = s0v.x + opb[0];
  float r1 = s0v.y + opb[1];
  float r2 = s0v.z + opb[2];
#pragma unroll
  for (int o = 0; o < 48; ++o) {
    const float f = facc[o] + s_fob[o];
    r0 += s_opw[o] * f; r1 += s_opw[48 + o] * f; r2 += s_opw[96 + o] * f;
  }
  out[((size_t)b * 3 + 0) * NPIX + gn] = r0;
  out[((size_t)b * 3 + 1) * NPIX + gn] = r1;
  out[((size_t)b * 3 + 2) * NPIX + gn] = r2;
}

extern "C" void kernel_launch(void* const* d_in, const int* in_sizes, int n_in,
                              void* d_out, int out_size, void* d_ws, size_t ws_size,
                              hipStream_t stream) {
  const float* x    = (const float*)d_in[0];
  const float* ipw  = (const float*)d_in[1];
  const float* ipb  = (const float*)d_in[2];
  const float* ln1w = (const float*)d_in[3];
  const float* ln1b = (const float*)d_in[4];
  const float* qw   = (const float*)d_in[5];
  const float* qb   = (const float*)d_in[6];
  const float* qdww = (const float*)d_in[7];
  const float* qdwb = (const float*)d_in[8];
  const float* temp = (const float*)d_in[9];
  const float* aow  = (const float*)d_in[10];
  const float* aob  = (const float*)d_in[11];
  const float* ln2w = (const float*)d_in[12];
  const float* ln2b = (const float*)d_in[13];
  const float* fiw  = (const float*)d_in[14];
  const float* fib  = (const float*)d_in[15];
  const float* fdww = (const float*)d_in[16];
  const float* fdwb = (const float*)d_in[17];
  const float* fow  = (const float*)d_in[18];
  const float* fob  = (const float*)d_in[19];
  const float* opw  = (const float*)d_in[20];
  const float* opb  = (const float*)d_in[21];

  const size_t s0Per = (size_t)NPIX * 16;
  int bc = 8;
  while (bc > 1 &&
         (size_t)bc * (REGPB + s0Per) + (5376 + 18432) * 4 > ws_size)
    bc >>= 1;
  char* region = (char*)d_ws;
  float4* s0arr = (float4*)(region + (size_t)bc * REGPB);
  float* red = (float*)((char*)s0arr + (size_t)bc * s0Per);
  float* Mws = red + 5376;
  hipMemsetAsync(red, 0, 5376 * sizeof(float), stream);
  for (int b0 = 0; b0 < 8; b0 += bc) {
    kA4<<<bc * 256, 256, 0, stream>>>(x + (size_t)b0 * 3 * NPIX, ipw, ipb,
                                      ln1w, ln1b, qw, qb, qdww, qdwb,
                                      region, red + b0 * 672);
    k3_attn<<<bc, 256, 0, stream>>>(red + b0 * 672, temp, aow,
                                    Mws + (size_t)b0 * 2304);
    k4a<<<bc * 256, 256, 0, stream>>>(region, s0arr, x + (size_t)b0 * 3 * NPIX,
                                      ipw, ipb, Mws + (size_t)b0 * 2304, aob,
                                      ln2w, ln2b, fiw, fib, opw);
    k5b<<<bc * 256, 256, 0, stream>>>(region, s0arr, fdww, fdwb, fow, fob,
                                      opw, opb,
                                      (float*)d_out + (size_t)b0 * 3 * NPIX);
  }
}

// Round 19
// 919.250 us; speedup vs baseline: 1.2510x; 1.0614x over previous
//
#include <hip/hip_runtime.h>
#include <hip/hip_fp16.h>

// CAPTNet block. B=8, CIN=3, H=W=256, DIM=48, HEADS=4 (ch=12), HID=96.
// Round 19: kA4 -> kA8 = the untested {dot2, sched_barrier} cell.
// Matrix: r13-15 {dot2, no barrier} spill ~430MB WRITE; r16 {FMA, barrier}
// clean but 628us (2x conv VALU). r16 changed both at once -- the
// sched_barrier(0) between the two per-pixel conv calls (preventing the
// compiler from interleaving both pixels' live sets) is plausibly the
// spill fix. kA8: analytic-LN staging (r15/r16-validated) + 1-px dot2 conv
// with sched_barrier between px calls + r16 pair-unit dwconv + r7 Gram.
// k3/k4a/k5b verbatim r18 (passing 975.7us, absmax 4.88e-4).
// region layout (r7): (b*256+gy)*98304 + chunk*4096 + gx*16, 24 chunks.
//   chunks 18..23: vdw fp16 (kA8 -> k4a); k4a writes y fp16 chunks 0..23.
// s0 (3 fp32) separate float4/pixel array (k4a -> k5b).

#define NPIX 65536
#define ROWB 98304        // bytes per (batch,row): 24 chunks * 4096
#define REGPB 25165824ull // bytes per batch in region
#define HSTRIDE 332       // k4a/k5b halo LDS row stride (half2 elems) [r7]
#define HA 324            // kA8 halo LDS row stride (u32/half2 elems)
#define KQ 258            // kA8 q/k fp16 LDS row stride (u32)

union F4U { float4 f4; unsigned int u[4]; };

typedef _Float16 h2f __attribute__((ext_vector_type(2)));
union U32H2 { unsigned int u; h2f h; };

__device__ __forceinline__ float2 uh2f(unsigned int u) {
  __half2 h; *(unsigned int*)&h = u; return __half22float2(h);
}
__device__ __forceinline__ unsigned int fpack(float a, float b) {
  __half2 h = __halves2half2(__float2half_rn(a), __float2half_rn(b));
  return *(unsigned int*)&h;
}
__device__ __forceinline__ float fdot2u(unsigned int a, unsigned int b, float c) {
  U32H2 ua, ub; ua.u = a; ub.u = b;
  return __builtin_amdgcn_fdot2(ua.h, ub.h, c, false);
}

// == kA8: in_proj+LN1(analytic)+qkv conv(dot2,1px,barrier)+dwconv+Gram+v ===
__global__ __launch_bounds__(256, 2) void kA8(
    const float* __restrict__ x, const float* __restrict__ ipw,
    const float* __restrict__ ipb, const float* __restrict__ lnw,
    const float* __restrict__ lnb, const float* __restrict__ qw,
    const float* __restrict__ qb, const float* __restrict__ dww,
    const float* __restrict__ dwb, char* __restrict__ region,
    float* __restrict__ red) {
  __shared__ unsigned int th[24 * HA];          // LN1 out, ch pairs fp16
  __shared__ unsigned int um[12 * HA];          // conv out 24ch fp16 pairs
  __shared__ unsigned int qsm[12 * KQ];         // q dwconv fp16 pairs (center)
  __shared__ unsigned int ksm[12 * KQ];         // k dwconv fp16 pairs
  __shared__ __align__(16) unsigned int wgp[576];  // conv w fp16 pairs [c2][o]
  __shared__ float qbf[24];
  __shared__ unsigned int dwp[72 * 9];          // dw w fp16 ch-pairs
  __shared__ unsigned int dbp[72];
  __shared__ float s_ipw[144], s_ipb[48], s_lnw[48], s_lnb[48];
  __shared__ float s_C[14];   // LN1 analytic scalars
  const int tid = threadIdx.x;
  for (int i = tid; i < 648; i += 256)
    dwp[i] = fpack(dww[(i / 9) * 18 + (i % 9)], dww[(i / 9) * 18 + 9 + (i % 9)]);
  if (tid < 72) dbp[tid] = fpack(dwb[2 * tid], dwb[2 * tid + 1]);
  if (tid < 144) s_ipw[tid] = ipw[tid];
  if (tid < 48) { s_ipb[tid] = ipb[tid]; s_lnw[tid] = lnw[tid]; s_lnb[tid] = lnb[tid]; }
  // 14 analytic-LN scalars (validated r15/r16)
  if (tid >= 192 && tid < 206) {
    const int e = tid - 192;
    float s = 0.f;
    if (e < 3) {
      for (int c = 0; c < 48; ++c) s += ipw[3 * c + e];
    } else if (e == 3) {
      for (int c = 0; c < 48; ++c) s += ipb[c];
    } else if (e < 10) {
      const int k0[6] = {0, 0, 0, 1, 1, 2}, k1[6] = {0, 1, 2, 1, 2, 2};
      const int a = k0[e - 4], bq = k1[e - 4];
      for (int c = 0; c < 48; ++c) s += ipw[3 * c + a] * ipw[3 * c + bq];
    } else if (e < 13) {
      for (int c = 0; c < 48; ++c) s += ipw[3 * c + (e - 10)] * ipb[c];
    } else {
      for (int c = 0; c < 48; ++c) s += ipb[c] * ipb[c];
    }
    s_C[e] = s;
  }
  const int b = blockIdx.x >> 8;
  const int tile = blockIdx.x & 255;
  const int ty0 = (tile >> 4) << 4, tx0 = (tile & 15) << 4;
  const int py = tid >> 4, px = tid & 15;
  const int hp = (py + 1) * 18 + (px + 1);
  char* regb = region + (size_t)b * REGPB;
  const int offs[9] = {-19, -18, -17, -1, 0, 1, 17, 18, 19};
  __syncthreads();

  auto stage_px = [&](int p) {   // p < 324 guaranteed by caller
    const int hy = p / 18, hx = p - hy * 18;
    const int gy = ty0 + hy - 1, gx = tx0 + hx - 1;
    const bool ok = ((unsigned)gy < 256u) && ((unsigned)gx < 256u);
    const int gn = (gy << 8) + gx;
    float x0 = 0.f, x1 = 0.f, x2 = 0.f;
    if (ok) {
      x0 = x[((size_t)b * 3 + 0) * NPIX + gn];
      x1 = x[((size_t)b * 3 + 1) * NPIX + gn];
      x2 = x[((size_t)b * 3 + 2) * NPIX + gn];
    }
    const float mu = (s_C[0]*x0 + s_C[1]*x1 + s_C[2]*x2 + s_C[3]) * (1.f/48.f);
    const float sumsq = s_C[4]*x0*x0 + s_C[7]*x1*x1 + s_C[9]*x2*x2
                      + 2.f*(s_C[5]*x0*x1 + s_C[6]*x0*x2 + s_C[8]*x1*x2
                             + s_C[10]*x0 + s_C[11]*x1 + s_C[12]*x2)
                      + s_C[13];
    const float var = sumsq * (1.f/48.f) - mu * mu;
    const float rs = rsqrtf(var + 1e-6f);
#pragma unroll
    for (int c2 = 0; c2 < 24; ++c2) {
      const float na = s_ipw[6*c2+0]*x0 + s_ipw[6*c2+1]*x1 + s_ipw[6*c2+2]*x2 + s_ipb[2*c2];
      const float nb = s_ipw[6*c2+3]*x0 + s_ipw[6*c2+4]*x1 + s_ipw[6*c2+5]*x2 + s_ipb[2*c2+1];
      th[c2 * HA + p] = fpack((na - mu) * rs * s_lnw[2*c2]   + s_lnb[2*c2],
                              (nb - mu) * rs * s_lnw[2*c2+1] + s_lnb[2*c2+1]);
    }
  };
  stage_px(tid);
  __builtin_amdgcn_sched_barrier(0);
  if (tid < 68) stage_px(tid + 256);
  __syncthreads();

  auto loadwg = [&](int cb) {   // pack conv weights: wgp[c2*24+o]=(w[o][2c2],w[o][2c2+1])
    for (int i = tid; i < 576; i += 256) {
      const int c2 = i / 24, o = i - c2 * 24;
      wgp[i] = fpack(qw[(cb + o) * 48 + 2 * c2], qw[(cb + o) * 48 + 2 * c2 + 1]);
    }
    if (tid < 24) qbf[tid] = qb[cb + tid];
  };
  auto conv_px = [&](int p) {   // conv 48->24 via dot2, ONE pixel
    const int hy = p / 18, hx = p - hy * 18;
    const int gy = ty0 + hy - 1, gx = tx0 + hx - 1;
    const bool ok = ((unsigned)gy < 256u) && ((unsigned)gx < 256u);
    float a[24];
#pragma unroll
    for (int j = 0; j < 24; ++j) a[j] = qbf[j];
#pragma unroll 4
    for (int c2 = 0; c2 < 24; ++c2) {
      const unsigned int t = th[c2 * HA + p];
      const uint4* wr = (const uint4*)&wgp[c2 * 24];
#pragma unroll
      for (int k = 0; k < 6; ++k) {
        const uint4 w = wr[k];
        a[4*k+0] = fdot2u(t, w.x, a[4*k+0]);
        a[4*k+1] = fdot2u(t, w.y, a[4*k+1]);
        a[4*k+2] = fdot2u(t, w.z, a[4*k+2]);
        a[4*k+3] = fdot2u(t, w.w, a[4*k+3]);
      }
    }
#pragma unroll
    for (int j = 0; j < 12; ++j)
      um[j * HA + p] = ok ? fpack(a[2 * j], a[2 * j + 1]) : 0u;
  };
  auto convPhase = [&]() {
    conv_px(tid);
    __builtin_amdgcn_sched_barrier(0);   // pin order: no cross-px live-set merge
    if (tid < 68) conv_px(tid + 256);
  };
  auto dwqk = [&](int cpb, unsigned int* dst) {   // dwconv, cpb = PAIR base
#pragma unroll
    for (int j = 0; j < 12; ++j) {
      const float2 db = uh2f(dbp[cpb + j]);
      float a = db.x, bb = db.y;
      const unsigned int* hrow = &um[j * HA + hp];
      const unsigned int* wp = &dwp[(cpb + j) * 9];
#pragma unroll
      for (int t = 0; t < 9; ++t) {
        const float2 f = uh2f(hrow[offs[t]]);
        const float2 w = uh2f(wp[t]);
        a += w.x * f.x; bb += w.y * f.y;
      }
      dst[j * KQ + tid] = fpack(a, bb);
    }
  };
  auto dwv = [&](int cpb, int chunk0) {   // dwconv v, cpb = PAIR base
    unsigned int vp[12];
#pragma unroll
    for (int j = 0; j < 12; ++j) {
      const float2 db = uh2f(dbp[cpb + j]);
      float a = db.x, bb = db.y;
      const unsigned int* hrow = &um[j * HA + hp];
      const unsigned int* wp = &dwp[(cpb + j) * 9];
#pragma unroll
      for (int t = 0; t < 9; ++t) {
        const float2 f = uh2f(hrow[offs[t]]);
        const float2 w = uh2f(wp[t]);
        a += w.x * f.x; bb += w.y * f.y;
      }
      vp[j] = fpack(a, bb);
    }
    char* vrow = regb + (size_t)(ty0 + py) * ROWB + ((tx0 + px) << 4);
#pragma unroll
    for (int q = 0; q < 3; ++q) {
      F4U u;
      u.u[0] = vp[4 * q]; u.u[1] = vp[4 * q + 1];
      u.u[2] = vp[4 * q + 2]; u.u[3] = vp[4 * q + 3];
      *(float4*)(vrow + (chunk0 + q) * 4096) = u.f4;
    }
  };
  auto gram2 = [&](int hbase) {   // 2 heads from fp16 qsm/ksm [r7 verbatim]
    for (int e = tid; e < 336; e += 256) {
      const int hh = e / 168, r2 = e - hh * 168;
      float s = 0.f;
      if (r2 < 144) {
        const int c = r2 / 12, d = r2 - (r2 / 12) * 12;
        const int qc = 12 * hh + c, kd = 12 * hh + d;
        const unsigned int* qr = &qsm[(qc >> 1) * KQ];
        const unsigned int* kr = &ksm[(kd >> 1) * KQ];
        const int q1 = qc & 1, k1 = kd & 1;
        for (int p = 0; p < 256; ++p) {
          const float2 fq = uh2f(qr[p]); const float2 fk = uh2f(kr[p]);
          s += (q1 ? fq.y : fq.x) * (k1 ? fk.y : fk.x);
        }
      } else if (r2 < 156) {
        const int qc = 12 * hh + (r2 - 144);
        const unsigned int* qr = &qsm[(qc >> 1) * KQ];
        const int q1 = qc & 1;
        for (int p = 0; p < 256; ++p) {
          const float2 fq = uh2f(qr[p]);
          const float v = q1 ? fq.y : fq.x;
          s += v * v;
        }
      } else {
        const int kd = 12 * hh + (r2 - 156);
        const unsigned int* kr = &ksm[(kd >> 1) * KQ];
        const int k1 = kd & 1;
        for (int p = 0; p < 256; ++p) {
          const float2 fk = uh2f(kr[p]);
          const float v = k1 ? fk.y : fk.x;
          s += v * v;
        }
      }
      atomicAdd(&red[b * 672 + (hbase + hh) * 168 + r2], s);
    }
  };

  loadwg(0);   __syncthreads(); convPhase(); __syncthreads(); dwqk(0, qsm);
  loadwg(48);  __syncthreads(); convPhase(); __syncthreads(); dwqk(24, ksm);
  __syncthreads(); gram2(0);
  loadwg(24);  __syncthreads(); convPhase(); __syncthreads(); dwqk(12, qsm);
  loadwg(72);  __syncthreads(); convPhase(); __syncthreads(); dwqk(36, ksm);
  __syncthreads(); gram2(2);
  loadwg(96);  __syncthreads(); convPhase(); __syncthreads(); dwv(48, 18);
  loadwg(120); __syncthreads(); convPhase(); __syncthreads(); dwv(60, 21);
}

// ================= k3: finalize attn, build fused M [r18 verbatim] ==========
__global__ __launch_bounds__(256) void k3_attn(const float* __restrict__ red,
                                               const float* __restrict__ temp,
                                               const float* __restrict__ aow,
                                               float* __restrict__ Mws) {
  __shared__ float attn[4 * 144];
  const int b = blockIdx.x, tid = threadIdx.x;
  const float* rb = red + b * 672;
  for (int e = tid; e < 576; e += 256) {
    const int h = e / 144, r = e - h * 144;
    const int c = r / 12, d = r - c * 12;
    const float g = rb[h * 168 + r];
    const float nq = fmaxf(sqrtf(rb[h * 168 + 144 + c]), 1e-12f);
    const float nk = fmaxf(sqrtf(rb[h * 168 + 156 + d]), 1e-12f);
    attn[e] = g / (nq * nk) * temp[h];
  }
  __syncthreads();
  if (tid < 48) {
    const int h = tid / 12, c = tid - h * 12;
    float* row = &attn[h * 144 + c * 12];
    float m = row[0];
    for (int d = 1; d < 12; ++d) m = fmaxf(m, row[d]);
    float s = 0.f;
    for (int d = 0; d < 12; ++d) { const float e2 = expf(row[d] - m); row[d] = e2; s += e2; }
    const float inv = 1.f / s;
    for (int d = 0; d < 12; ++d) row[d] *= inv;
  }
  __syncthreads();
  for (int e = tid; e < 2304; e += 256) {
    const int o = e / 48, j = e - o * 48;
    const int h = j / 12, d = j - h * 12;
    float s = 0.f;
    for (int c = 0; c < 12; ++c)
      s += aow[o * 48 + h * 12 + c] * attn[h * 144 + c * 12 + d];
    Mws[b * 2304 + e] = s;
  }
}

// ==== k4a: recompute in_proj, attn-out, LN2, ffn_in [r18 verbatim] ==========
__global__ __launch_bounds__(256, 2) void k4a(
    char* __restrict__ region, float4* __restrict__ s0arr,
    const float* __restrict__ x, const float* __restrict__ ipw,
    const float* __restrict__ ipb, const float* __restrict__ Mws,
    const float* __restrict__ aob, const float* __restrict__ lnw,
    const float* __restrict__ lnb, const float* __restrict__ fiw,
    const float* __restrict__ fib, const float* __restrict__ opw) {
  __shared__ __align__(16) float MT[48 * 48];     // MT[j][o]
  __shared__ __align__(16) float wT2[48 * 192];   // wT2[c][pos], pos interleaved
  __shared__ float s_aob[48], s_lnw[48], s_lnb[48], s_fib2[192], s_opw[144];
  __shared__ float s_ipw[144], s_ipb[48];
  const int tid = threadIdx.x;
  const int b = blockIdx.x >> 8;
  const int gy = blockIdx.x & 255;
  const int n = (gy << 8) + tid;
  for (int i = tid; i < 2304; i += 256) {
    const int o = i / 48, j = i - o * 48;
    MT[j * 48 + o] = Mws[b * 2304 + i];
  }
  for (int i = tid; i < 9216; i += 256) {
    const int c = i / 192, pos = i - c * 192;
    const int ch = (pos & 1) ? 96 + (pos >> 1) : (pos >> 1);
    wT2[i] = fiw[ch * 48 + c];
  }
  if (tid < 192) {
    const int ch = (tid & 1) ? 96 + (tid >> 1) : (tid >> 1);
    s_fib2[tid] = fib[ch];
  }
  if (tid < 144) { s_opw[tid] = opw[tid]; s_ipw[tid] = ipw[tid]; }
  if (tid < 48) {
    s_aob[tid] = aob[tid]; s_lnw[tid] = lnw[tid]; s_lnb[tid] = lnb[tid];
    s_ipb[tid] = ipb[tid];
  }
  __syncthreads();
  char* rowp = region + (size_t)((b << 8) + gy) * ROWB + (tid << 4);
  float vv[48];
#pragma unroll
  for (int q = 0; q < 6; ++q) {
    F4U u; u.f4 = *(const float4*)(rowp + (18 + q) * 4096);
#pragma unroll
    for (int j = 0; j < 4; ++j) {
      const float2 f = uh2f(u.u[j]);
      vv[8 * q + 2 * j] = f.x; vv[8 * q + 2 * j + 1] = f.y;
    }
  }
  float y[48];
#pragma unroll
  for (int o = 0; o < 48; ++o) y[o] = s_aob[o];
#pragma unroll 4
  for (int j = 0; j < 48; ++j) {
    const float vj = vv[j];
    const float* mr = &MT[j * 48];
#pragma unroll
    for (int o4 = 0; o4 < 12; ++o4) {
      const float4 m = *(const float4*)&mr[o4 * 4];
      y[o4 * 4 + 0] += m.x * vj; y[o4 * 4 + 1] += m.y * vj;
      y[o4 * 4 + 2] += m.z * vj; y[o4 * 4 + 3] += m.w * vj;
    }
  }
  // recompute in_proj (xp) and add residual
  const float x0 = x[((size_t)b * 3 + 0) * NPIX + n];
  const float x1 = x[((size_t)b * 3 + 1) * NPIX + n];
  const float x2 = x[((size_t)b * 3 + 2) * NPIX + n];
  float mu = 0.f;
#pragma unroll
  for (int c = 0; c < 48; ++c) {
    y[c] += s_ipw[c * 3] * x0 + s_ipw[c * 3 + 1] * x1 + s_ipw[c * 3 + 2] * x2 + s_ipb[c];
    mu += y[c];
  }
  float s0 = 0.f, s1 = 0.f, s2 = 0.f;
#pragma unroll
  for (int c = 0; c < 48; ++c) {
    s0 += s_opw[c] * y[c]; s1 += s_opw[48 + c] * y[c]; s2 += s_opw[96 + c] * y[c];
  }
  float4 s0v; s0v.x = s0; s0v.y = s1; s0v.z = s2; s0v.w = 0.f;
  s0arr[(size_t)b * NPIX + n] = s0v;
  mu *= (1.f / 48.f);
  float var = 0.f;
#pragma unroll
  for (int c = 0; c < 48; ++c) { const float d = y[c] - mu; var += d * d; }
  const float rs2 = rsqrtf(var * (1.f / 48.f) + 1e-6f);
#pragma unroll
  for (int c = 0; c < 48; ++c) y[c] = (y[c] - mu) * rs2 * s_lnw[c] + s_lnb[c];
#pragma unroll
  for (int ob = 0; ob < 12; ++ob) {
    const int o0 = ob * 16;
    float acc[16];
#pragma unroll
    for (int j = 0; j < 16; ++j) acc[j] = s_fib2[o0 + j];
#pragma unroll 4
    for (int c = 0; c < 48; ++c) {
      const float xv = y[c];
      const float4 w0 = *(const float4*)&wT2[c * 192 + o0];
      const float4 w1 = *(const float4*)&wT2[c * 192 + o0 + 4];
      const float4 w2 = *(const float4*)&wT2[c * 192 + o0 + 8];
      const float4 w3 = *(const float4*)&wT2[c * 192 + o0 + 12];
      acc[0] += w0.x * xv; acc[1] += w0.y * xv; acc[2] += w0.z * xv; acc[3] += w0.w * xv;
      acc[4] += w1.x * xv; acc[5] += w1.y * xv; acc[6] += w1.z * xv; acc[7] += w1.w * xv;
      acc[8] += w2.x * xv; acc[9] += w2.y * xv; acc[10] += w2.z * xv; acc[11] += w2.w * xv;
      acc[12] += w3.x * xv; acc[13] += w3.y * xv; acc[14] += w3.z * xv; acc[15] += w3.w * xv;
    }
    F4U u;
    u.u[0] = fpack(acc[0], acc[1]);   u.u[1] = fpack(acc[2], acc[3]);
    u.u[2] = fpack(acc[4], acc[5]);   u.u[3] = fpack(acc[6], acc[7]);
    *(float4*)(rowp + (2 * ob) * 4096) = u.f4;
    u.u[0] = fpack(acc[8], acc[9]);   u.u[1] = fpack(acc[10], acc[11]);
    u.u[2] = fpack(acc[12], acc[13]); u.u[3] = fpack(acc[14], acc[15]);
    *(float4*)(rowp + (2 * ob + 1) * 4096) = u.f4;
  }
}

// ====== k5b: dw + SimpleGate + ffn_out + out_proj [r18 verbatim] ============
__global__ __launch_bounds__(256, 2) void k5b(
    const char* __restrict__ region, const float4* __restrict__ s0arr,
    const float* __restrict__ fdww, const float* __restrict__ fdwb,
    const float* __restrict__ fow, const float* __restrict__ fob,
    const float* __restrict__ opw, const float* __restrict__ opb,
    float* __restrict__ out) {
  __shared__ unsigned int halo[12 * HSTRIDE];
  __shared__ __align__(16) float fowT[96 * 48];   // fowT[c1][o] = fow[o][c1]
  __shared__ float s_dww2[1728], s_dwb2[192], s_opw[144], s_fob[48];
  const int tid = threadIdx.x;
  for (int i = tid; i < 4608; i += 256) {
    const int c = i / 48, o = i - c * 48;
    fowT[i] = fow[o * 96 + c];
  }
  for (int i = tid; i < 1728; i += 256) {
    const int P = i / 9, t = i - P * 9;
    const int ch = (P & 1) ? 96 + (P >> 1) : (P >> 1);
    s_dww2[i] = fdww[ch * 9 + t];
  }
  if (tid < 192) {
    const int ch = (tid & 1) ? 96 + (tid >> 1) : (tid >> 1);
    s_dwb2[tid] = fdwb[ch];
  }
  if (tid < 144) s_opw[tid] = opw[tid];
  if (tid < 48) s_fob[tid] = fob[tid];
  const int b = blockIdx.x >> 8;
  const int tile = blockIdx.x & 255;
  const int ty0 = (tile >> 4) << 4, tx0 = (tile & 15) << 4;
  const int py = tid >> 4, px = tid & 15;
  const int hp = (py + 1) * 18 + (px + 1);
  const int gn = ((ty0 + py) << 8) + (tx0 + px);
  const char* regb = region + (size_t)b * REGPB;

  float4 pf[4];
  auto prefetch = [&](int cb) {
#pragma unroll
    for (int r = 0; r < 4; ++r) {
      const int i = tid + (r << 8);
      float4 z = {0.f, 0.f, 0.f, 0.f}; pf[r] = z;
      if (i < 972) {
        const int c4 = i / 324, p = i - c4 * 324;
        const int hy = p / 18, hx = p - hy * 18;
        const int gy = ty0 + hy - 1, gx = tx0 + hx - 1;
        if (((unsigned)gy < 256u) && ((unsigned)gx < 256u))
          pf[r] = *(const float4*)(regb + (size_t)gy * ROWB + (cb + c4) * 4096 + (gx << 4));
      }
    }
  };
  auto commit = [&]() {
#pragma unroll
    for (int r = 0; r < 4; ++r) {
      const int i = tid + (r << 8);
      if (i < 972) {
        const int c4 = i / 324, p = i - c4 * 324;
        F4U u; u.f4 = pf[r];
        const int pb = c4 << 2;
#pragma unroll
        for (int j = 0; j < 4; ++j) halo[(pb + j) * HSTRIDE + p] = u.u[j];
      }
    }
  };

  float facc[48];
#pragma unroll
  for (int o = 0; o < 48; ++o) facc[o] = 0.f;
  prefetch(0);
  for (int s = 0; s < 8; ++s) {
    __syncthreads(); commit(); __syncthreads();
    if (s < 7) prefetch(3 * (s + 1));
    const int offs[9] = {-19, -18, -17, -1, 0, 1, 17, 18, 19};
#pragma unroll
    for (int pp = 0; pp < 12; ++pp) {
      const int P = 24 * s + 2 * pp;
      const float* w0 = &s_dww2[P * 9];
      const float* w1 = w0 + 9;
      const unsigned int* hrow = &halo[pp * HSTRIDE + hp];
      float a = s_dwb2[P], b2 = s_dwb2[P + 1];
#pragma unroll
      for (int t = 0; t < 9; ++t) {
        const float2 f = uh2f(hrow[offs[t]]);
        a += w0[t] * f.x; b2 += w1[t] * f.y;
      }
      const float gate = a * b2;
      const float* fr = &fowT[(12 * s + pp) * 48];
#pragma unroll
      for (int o4 = 0; o4 < 12; ++o4) {
        const float4 m = *(const float4*)&fr[o4 * 4];
        facc[o4 * 4 + 0] += m.x * gate; facc[o4 * 4 + 1] += m.y * gate;
        facc[o4 * 4 + 2] += m.z * gate; facc[o4 * 4 + 3] += m.w * gate;
      }
    }
  }
  const float4 s0v = s0arr[(size_t)b * NPIX + gn];
  float r0 = s0v.x + opb[0];
  float r1 = s0v.y + opb[1];
  float r2 = s0v.z + opb[2];
#pragma unroll
  for (int o = 0; o < 48; ++o) {
    const float f = facc[o] + s_fob[o];
    r0 += s_opw[o] * f; r1 += s_opw[48 + o] * f; r2 += s_opw[96 + o] * f;
  }
  out[((size_t)b * 3 + 0) * NPIX + gn] = r0;
  out[((size_t)b * 3 + 1) * NPIX + gn] = r1;
  out[((size_t)b * 3 + 2) * NPIX + gn] = r2;
}

extern "C" void kernel_launch(void* const* d_in, const int* in_sizes, int n_in,
                              void* d_out, int out_size, void* d_ws, size_t ws_size,
                              hipStream_t stream) {
  const float* x    = (const float*)d_in[0];
  const float* ipw  = (const float*)d_in[1];
  const float* ipb  = (const float*)d_in[2];
  const float* ln1w = (const float*)d_in[3];
  const float* ln1b = (const float*)d_in[4];
  const float* qw   = (const float*)d_in[5];
  const float* qb   = (const float*)d_in[6];
  const float* qdww = (const float*)d_in[7];
  const float* qdwb = (const float*)d_in[8];
  const float* temp = (const float*)d_in[9];
  const float* aow  = (const float*)d_in[10];
  const float* aob  = (const float*)d_in[11];
  const float* ln2w = (const float*)d_in[12];
  const float* ln2b = (const float*)d_in[13];
  const float* fiw  = (const float*)d_in[14];
  const float* fib  = (const float*)d_in[15];
  const float* fdww = (const float*)d_in[16];
  const float* fdwb = (const float*)d_in[17];
  const float* fow  = (const float*)d_in[18];
  const float* fob  = (const float*)d_in[19];
  const float* opw  = (const float*)d_in[20];
  const float* opb  = (const float*)d_in[21];

  const size_t s0Per = (size_t)NPIX * 16;
  int bc = 8;
  while (bc > 1 &&
         (size_t)bc * (REGPB + s0Per) + (5376 + 18432) * 4 > ws_size)
    bc >>= 1;
  char* region = (char*)d_ws;
  float4* s0arr = (float4*)(region + (size_t)bc * REGPB);
  float* red = (float*)((char*)s0arr + (size_t)bc * s0Per);
  float* Mws = red + 5376;
  hipMemsetAsync(red, 0, 5376 * sizeof(float), stream);
  for (int b0 = 0; b0 < 8; b0 += bc) {
    kA8<<<bc * 256, 256, 0, stream>>>(x + (size_t)b0 * 3 * NPIX, ipw, ipb,
                                      ln1w, ln1b, qw, qb, qdww, qdwb,
                                      region, red + b0 * 672);
    k3_attn<<<bc, 256, 0, stream>>>(red + b0 * 672, temp, aow,
                                    Mws + (size_t)b0 * 2304);
    k4a<<<bc * 256, 256, 0, stream>>>(region, s0arr, x + (size_t)b0 * 3 * NPIX,
                                      ipw, ipb, Mws + (size_t)b0 * 2304, aob,
                                      ln2w, ln2b, fiw, fib, opw);
    k5b<<<bc * 256, 256, 0, stream>>>(region, s0arr, fdww, fdwb, fow, fob,
                                      opw, opb,
                                      (float*)d_out + (size_t)b0 * 3 * NPIX);
  }
}

// Round 20
// 917.995 us; speedup vs baseline: 1.2527x; 1.0014x over previous
//
#include <hip/hip_runtime.h>
#include <hip/hip_fp16.h>

// CAPTNet block. B=8, CIN=3, H=W=256, DIM=48, HEADS=4 (ch=12), HID=96.
// Round 20: r19 with k4a reverted to __launch_bounds__(256,3).
// r19 counters: k4a at (256,2) = 475us, VGPR STILL 68, spill traffic
// unchanged (361+576 MB) -- the compiler ignored the (256,2) headroom
// (scheduler-induced spill, same as kA's), and the occupancy drop 3->2
// blocks/CU made the spill less hideable (r7 measured 396us at (256,3)).
// k5b keeps (256,2) (genuinely fit under 128: dropped ~130 -> ~30-60us).
// kA8 (dot2 + sched_barrier, clean, 403us) and k3 verbatim r19.
// region layout (r7): (b*256+gy)*98304 + chunk*4096 + gx*16, 24 chunks.
//   chunks 18..23: vdw fp16 (kA8 -> k4a); k4a writes y fp16 chunks 0..23.
// s0 (3 fp32) separate float4/pixel array (k4a -> k5b).

#define NPIX 65536
#define ROWB 98304        // bytes per (batch,row): 24 chunks * 4096
#define REGPB 25165824ull // bytes per batch in region
#define HSTRIDE 332       // k4a/k5b halo LDS row stride (half2 elems) [r7]
#define HA 324            // kA8 halo LDS row stride (u32/half2 elems)
#define KQ 258            // kA8 q/k fp16 LDS row stride (u32)

union F4U { float4 f4; unsigned int u[4]; };

typedef _Float16 h2f __attribute__((ext_vector_type(2)));
union U32H2 { unsigned int u; h2f h; };

__device__ __forceinline__ float2 uh2f(unsigned int u) {
  __half2 h; *(unsigned int*)&h = u; return __half22float2(h);
}
__device__ __forceinline__ unsigned int fpack(float a, float b) {
  __half2 h = __halves2half2(__float2half_rn(a), __float2half_rn(b));
  return *(unsigned int*)&h;
}
__device__ __forceinline__ float fdot2u(unsigned int a, unsigned int b, float c) {
  U32H2 ua, ub; ua.u = a; ub.u = b;
  return __builtin_amdgcn_fdot2(ua.h, ub.h, c, false);
}

// == kA8: in_proj+LN1(analytic)+qkv conv(dot2,1px,barrier)+dwconv+Gram+v ===
__global__ __launch_bounds__(256, 2) void kA8(
    const float* __restrict__ x, const float* __restrict__ ipw,
    const float* __restrict__ ipb, const float* __restrict__ lnw,
    const float* __restrict__ lnb, const float* __restrict__ qw,
    const float* __restrict__ qb, const float* __restrict__ dww,
    const float* __restrict__ dwb, char* __restrict__ region,
    float* __restrict__ red) {
  __shared__ unsigned int th[24 * HA];          // LN1 out, ch pairs fp16
  __shared__ unsigned int um[12 * HA];          // conv out 24ch fp16 pairs
  __shared__ unsigned int qsm[12 * KQ];         // q dwconv fp16 pairs (center)
  __shared__ unsigned int ksm[12 * KQ];         // k dwconv fp16 pairs
  __shared__ __align__(16) unsigned int wgp[576];  // conv w fp16 pairs [c2][o]
  __shared__ float qbf[24];
  __shared__ unsigned int dwp[72 * 9];          // dw w fp16 ch-pairs
  __shared__ unsigned int dbp[72];
  __shared__ float s_ipw[144], s_ipb[48], s_lnw[48], s_lnb[48];
  __shared__ float s_C[14];   // LN1 analytic scalars
  const int tid = threadIdx.x;
  for (int i = tid; i < 648; i += 256)
    dwp[i] = fpack(dww[(i / 9) * 18 + (i % 9)], dww[(i / 9) * 18 + 9 + (i % 9)]);
  if (tid < 72) dbp[tid] = fpack(dwb[2 * tid], dwb[2 * tid + 1]);
  if (tid < 144) s_ipw[tid] = ipw[tid];
  if (tid < 48) { s_ipb[tid] = ipb[tid]; s_lnw[tid] = lnw[tid]; s_lnb[tid] = lnb[tid]; }
  // 14 analytic-LN scalars (validated r15/r16/r19)
  if (tid >= 192 && tid < 206) {
    const int e = tid - 192;
    float s = 0.f;
    if (e < 3) {
      for (int c = 0; c < 48; ++c) s += ipw[3 * c + e];
    } else if (e == 3) {
      for (int c = 0; c < 48; ++c) s += ipb[c];
    } else if (e < 10) {
      const int k0[6] = {0, 0, 0, 1, 1, 2}, k1[6] = {0, 1, 2, 1, 2, 2};
      const int a = k0[e - 4], bq = k1[e - 4];
      for (int c = 0; c < 48; ++c) s += ipw[3 * c + a] * ipw[3 * c + bq];
    } else if (e < 13) {
      for (int c = 0; c < 48; ++c) s += ipw[3 * c + (e - 10)] * ipb[c];
    } else {
      for (int c = 0; c < 48; ++c) s += ipb[c] * ipb[c];
    }
    s_C[e] = s;
  }
  const int b = blockIdx.x >> 8;
  const int tile = blockIdx.x & 255;
  const int ty0 = (tile >> 4) << 4, tx0 = (tile & 15) << 4;
  const int py = tid >> 4, px = tid & 15;
  const int hp = (py + 1) * 18 + (px + 1);
  char* regb = region + (size_t)b * REGPB;
  const int offs[9] = {-19, -18, -17, -1, 0, 1, 17, 18, 19};
  __syncthreads();

  auto stage_px = [&](int p) {   // p < 324 guaranteed by caller
    const int hy = p / 18, hx = p - hy * 18;
    const int gy = ty0 + hy - 1, gx = tx0 + hx - 1;
    const bool ok = ((unsigned)gy < 256u) && ((unsigned)gx < 256u);
    const int gn = (gy << 8) + gx;
    float x0 = 0.f, x1 = 0.f, x2 = 0.f;
    if (ok) {
      x0 = x[((size_t)b * 3 + 0) * NPIX + gn];
      x1 = x[((size_t)b * 3 + 1) * NPIX + gn];
      x2 = x[((size_t)b * 3 + 2) * NPIX + gn];
    }
    const float mu = (s_C[0]*x0 + s_C[1]*x1 + s_C[2]*x2 + s_C[3]) * (1.f/48.f);
    const float sumsq = s_C[4]*x0*x0 + s_C[7]*x1*x1 + s_C[9]*x2*x2
                      + 2.f*(s_C[5]*x0*x1 + s_C[6]*x0*x2 + s_C[8]*x1*x2
                             + s_C[10]*x0 + s_C[11]*x1 + s_C[12]*x2)
                      + s_C[13];
    const float var = sumsq * (1.f/48.f) - mu * mu;
    const float rs = rsqrtf(var + 1e-6f);
#pragma unroll
    for (int c2 = 0; c2 < 24; ++c2) {
      const float na = s_ipw[6*c2+0]*x0 + s_ipw[6*c2+1]*x1 + s_ipw[6*c2+2]*x2 + s_ipb[2*c2];
      const float nb = s_ipw[6*c2+3]*x0 + s_ipw[6*c2+4]*x1 + s_ipw[6*c2+5]*x2 + s_ipb[2*c2+1];
      th[c2 * HA + p] = fpack((na - mu) * rs * s_lnw[2*c2]   + s_lnb[2*c2],
                              (nb - mu) * rs * s_lnw[2*c2+1] + s_lnb[2*c2+1]);
    }
  };
  stage_px(tid);
  __builtin_amdgcn_sched_barrier(0);
  if (tid < 68) stage_px(tid + 256);
  __syncthreads();

  auto loadwg = [&](int cb) {   // pack conv weights: wgp[c2*24+o]=(w[o][2c2],w[o][2c2+1])
    for (int i = tid; i < 576; i += 256) {
      const int c2 = i / 24, o = i - c2 * 24;
      wgp[i] = fpack(qw[(cb + o) * 48 + 2 * c2], qw[(cb + o) * 48 + 2 * c2 + 1]);
    }
    if (tid < 24) qbf[tid] = qb[cb + tid];
  };
  auto conv_px = [&](int p) {   // conv 48->24 via dot2, ONE pixel
    const int hy = p / 18, hx = p - hy * 18;
    const int gy = ty0 + hy - 1, gx = tx0 + hx - 1;
    const bool ok = ((unsigned)gy < 256u) && ((unsigned)gx < 256u);
    float a[24];
#pragma unroll
    for (int j = 0; j < 24; ++j) a[j] = qbf[j];
#pragma unroll 4
    for (int c2 = 0; c2 < 24; ++c2) {
      const unsigned int t = th[c2 * HA + p];
      const uint4* wr = (const uint4*)&wgp[c2 * 24];
#pragma unroll
      for (int k = 0; k < 6; ++k) {
        const uint4 w = wr[k];
        a[4*k+0] = fdot2u(t, w.x, a[4*k+0]);
        a[4*k+1] = fdot2u(t, w.y, a[4*k+1]);
        a[4*k+2] = fdot2u(t, w.z, a[4*k+2]);
        a[4*k+3] = fdot2u(t, w.w, a[4*k+3]);
      }
    }
#pragma unroll
    for (int j = 0; j < 12; ++j)
      um[j * HA + p] = ok ? fpack(a[2 * j], a[2 * j + 1]) : 0u;
  };
  auto convPhase = [&]() {
    conv_px(tid);
    __builtin_amdgcn_sched_barrier(0);   // pin order: no cross-px live-set merge
    if (tid < 68) conv_px(tid + 256);
  };
  auto dwqk = [&](int cpb, unsigned int* dst) {   // dwconv, cpb = PAIR base
#pragma unroll
    for (int j = 0; j < 12; ++j) {
      const float2 db = uh2f(dbp[cpb + j]);
      float a = db.x, bb = db.y;
      const unsigned int* hrow = &um[j * HA + hp];
      const unsigned int* wp = &dwp[(cpb + j) * 9];
#pragma unroll
      for (int t = 0; t < 9; ++t) {
        const float2 f = uh2f(hrow[offs[t]]);
        const float2 w = uh2f(wp[t]);
        a += w.x * f.x; bb += w.y * f.y;
      }
      dst[j * KQ + tid] = fpack(a, bb);
    }
  };
  auto dwv = [&](int cpb, int chunk0) {   // dwconv v, cpb = PAIR base
    unsigned int vp[12];
#pragma unroll
    for (int j = 0; j < 12; ++j) {
      const float2 db = uh2f(dbp[cpb + j]);
      float a = db.x, bb = db.y;
      const unsigned int* hrow = &um[j * HA + hp];
      const unsigned int* wp = &dwp[(cpb + j) * 9];
#pragma unroll
      for (int t = 0; t < 9; ++t) {
        const float2 f = uh2f(hrow[offs[t]]);
        const float2 w = uh2f(wp[t]);
        a += w.x * f.x; bb += w.y * f.y;
      }
      vp[j] = fpack(a, bb);
    }
    char* vrow = regb + (size_t)(ty0 + py) * ROWB + ((tx0 + px) << 4);
#pragma unroll
    for (int q = 0; q < 3; ++q) {
      F4U u;
      u.u[0] = vp[4 * q]; u.u[1] = vp[4 * q + 1];
      u.u[2] = vp[4 * q + 2]; u.u[3] = vp[4 * q + 3];
      *(float4*)(vrow + (chunk0 + q) * 4096) = u.f4;
    }
  };
  auto gram2 = [&](int hbase) {   // 2 heads from fp16 qsm/ksm [r7 verbatim]
    for (int e = tid; e < 336; e += 256) {
      const int hh = e / 168, r2 = e - hh * 168;
      float s = 0.f;
      if (r2 < 144) {
        const int c = r2 / 12, d = r2 - (r2 / 12) * 12;
        const int qc = 12 * hh + c, kd = 12 * hh + d;
        const unsigned int* qr = &qsm[(qc >> 1) * KQ];
        const unsigned int* kr = &ksm[(kd >> 1) * KQ];
        const int q1 = qc & 1, k1 = kd & 1;
        for (int p = 0; p < 256; ++p) {
          const float2 fq = uh2f(qr[p]); const float2 fk = uh2f(kr[p]);
          s += (q1 ? fq.y : fq.x) * (k1 ? fk.y : fk.x);
        }
      } else if (r2 < 156) {
        const int qc = 12 * hh + (r2 - 144);
        const unsigned int* qr = &qsm[(qc >> 1) * KQ];
        const int q1 = qc & 1;
        for (int p = 0; p < 256; ++p) {
          const float2 fq = uh2f(qr[p]);
          const float v = q1 ? fq.y : fq.x;
          s += v * v;
        }
      } else {
        const int kd = 12 * hh + (r2 - 156);
        const unsigned int* kr = &ksm[(kd >> 1) * KQ];
        const int k1 = kd & 1;
        for (int p = 0; p < 256; ++p) {
          const float2 fk = uh2f(kr[p]);
          const float v = k1 ? fk.y : fk.x;
          s += v * v;
        }
      }
      atomicAdd(&red[b * 672 + (hbase + hh) * 168 + r2], s);
    }
  };

  loadwg(0);   __syncthreads(); convPhase(); __syncthreads(); dwqk(0, qsm);
  loadwg(48);  __syncthreads(); convPhase(); __syncthreads(); dwqk(24, ksm);
  __syncthreads(); gram2(0);
  loadwg(24);  __syncthreads(); convPhase(); __syncthreads(); dwqk(12, qsm);
  loadwg(72);  __syncthreads(); convPhase(); __syncthreads(); dwqk(36, ksm);
  __syncthreads(); gram2(2);
  loadwg(96);  __syncthreads(); convPhase(); __syncthreads(); dwv(48, 18);
  loadwg(120); __syncthreads(); convPhase(); __syncthreads(); dwv(60, 21);
}

// ================= k3: finalize attn, build fused M [r19 verbatim] ==========
__global__ __launch_bounds__(256) void k3_attn(const float* __restrict__ red,
                                               const float* __restrict__ temp,
                                               const float* __restrict__ aow,
                                               float* __restrict__ Mws) {
  __shared__ float attn[4 * 144];
  const int b = blockIdx.x, tid = threadIdx.x;
  const float* rb = red + b * 672;
  for (int e = tid; e < 576; e += 256) {
    const int h = e / 144, r = e - h * 144;
    const int c = r / 12, d = r - c * 12;
    const float g = rb[h * 168 + r];
    const float nq = fmaxf(sqrtf(rb[h * 168 + 144 + c]), 1e-12f);
    const float nk = fmaxf(sqrtf(rb[h * 168 + 156 + d]), 1e-12f);
    attn[e] = g / (nq * nk) * temp[h];
  }
  __syncthreads();
  if (tid < 48) {
    const int h = tid / 12, c = tid - h * 12;
    float* row = &attn[h * 144 + c * 12];
    float m = row[0];
    for (int d = 1; d < 12; ++d) m = fmaxf(m, row[d]);
    float s = 0.f;
    for (int d = 0; d < 12; ++d) { const float e2 = expf(row[d] - m); row[d] = e2; s += e2; }
    const float inv = 1.f / s;
    for (int d = 0; d < 12; ++d) row[d] *= inv;
  }
  __syncthreads();
  for (int e = tid; e < 2304; e += 256) {
    const int o = e / 48, j = e - o * 48;
    const int h = j / 12, d = j - h * 12;
    float s = 0.f;
    for (int c = 0; c < 12; ++c)
      s += aow[o * 48 + h * 12 + c] * attn[h * 144 + c * 12 + d];
    Mws[b * 2304 + e] = s;
  }
}

// ==== k4a: recompute in_proj, attn-out, LN2, ffn_in [(256,3), r7-measured] ==
__global__ __launch_bounds__(256, 3) void k4a(
    char* __restrict__ region, float4* __restrict__ s0arr,
    const float* __restrict__ x, const float* __restrict__ ipw,
    const float* __restrict__ ipb, const float* __restrict__ Mws,
    const float* __restrict__ aob, const float* __restrict__ lnw,
    const float* __restrict__ lnb, const float* __restrict__ fiw,
    const float* __restrict__ fib, const float* __restrict__ opw) {
  __shared__ __align__(16) float MT[48 * 48];     // MT[j][o]
  __shared__ __align__(16) float wT2[48 * 192];   // wT2[c][pos], pos interleaved
  __shared__ float s_aob[48], s_lnw[48], s_lnb[48], s_fib2[192], s_opw[144];
  __shared__ float s_ipw[144], s_ipb[48];
  const int tid = threadIdx.x;
  const int b = blockIdx.x >> 8;
  const int gy = blockIdx.x & 255;
  const int n = (gy << 8) + tid;
  for (int i = tid; i < 2304; i += 256) {
    const int o = i / 48, j = i - o * 48;
    MT[j * 48 + o] = Mws[b * 2304 + i];
  }
  for (int i = tid; i < 9216; i += 256) {
    const int c = i / 192, pos = i - c * 192;
    const int ch = (pos & 1) ? 96 + (pos >> 1) : (pos >> 1);
    wT2[i] = fiw[ch * 48 + c];
  }
  if (tid < 192) {
    const int ch = (tid & 1) ? 96 + (tid >> 1) : (tid >> 1);
    s_fib2[tid] = fib[ch];
  }
  if (tid < 144) { s_opw[tid] = opw[tid]; s_ipw[tid] = ipw[tid]; }
  if (tid < 48) {
    s_aob[tid] = aob[tid]; s_lnw[tid] = lnw[tid]; s_lnb[tid] = lnb[tid];
    s_ipb[tid] = ipb[tid];
  }
  __syncthreads();
  char* rowp = region + (size_t)((b << 8) + gy) * ROWB + (tid << 4);
  float vv[48];
#pragma unroll
  for (int q = 0; q < 6; ++q) {
    F4U u; u.f4 = *(const float4*)(rowp + (18 + q) * 4096);
#pragma unroll
    for (int j = 0; j < 4; ++j) {
      const float2 f = uh2f(u.u[j]);
      vv[8 * q + 2 * j] = f.x; vv[8 * q + 2 * j + 1] = f.y;
    }
  }
  float y[48];
#pragma unroll
  for (int o = 0; o < 48; ++o) y[o] = s_aob[o];
#pragma unroll 4
  for (int j = 0; j < 48; ++j) {
    const float vj = vv[j];
    const float* mr = &MT[j * 48];
#pragma unroll
    for (int o4 = 0; o4 < 12; ++o4) {
      const float4 m = *(const float4*)&mr[o4 * 4];
      y[o4 * 4 + 0] += m.x * vj; y[o4 * 4 + 1] += m.y * vj;
      y[o4 * 4 + 2] += m.z * vj; y[o4 * 4 + 3] += m.w * vj;
    }
  }
  // recompute in_proj (xp) and add residual
  const float x0 = x[((size_t)b * 3 + 0) * NPIX + n];
  const float x1 = x[((size_t)b * 3 + 1) * NPIX + n];
  const float x2 = x[((size_t)b * 3 + 2) * NPIX + n];
  float mu = 0.f;
#pragma unroll
  for (int c = 0; c < 48; ++c) {
    y[c] += s_ipw[c * 3] * x0 + s_ipw[c * 3 + 1] * x1 + s_ipw[c * 3 + 2] * x2 + s_ipb[c];
    mu += y[c];
  }
  float s0 = 0.f, s1 = 0.f, s2 = 0.f;
#pragma unroll
  for (int c = 0; c < 48; ++c) {
    s0 += s_opw[c] * y[c]; s1 += s_opw[48 + c] * y[c]; s2 += s_opw[96 + c] * y[c];
  }
  float4 s0v; s0v.x = s0; s0v.y = s1; s0v.z = s2; s0v.w = 0.f;
  s0arr[(size_t)b * NPIX + n] = s0v;
  mu *= (1.f / 48.f);
  float var = 0.f;
#pragma unroll
  for (int c = 0; c < 48; ++c) { const float d = y[c] - mu; var += d * d; }
  const float rs2 = rsqrtf(var * (1.f / 48.f) + 1e-6f);
#pragma unroll
  for (int c = 0; c < 48; ++c) y[c] = (y[c] - mu) * rs2 * s_lnw[c] + s_lnb[c];
#pragma unroll
  for (int ob = 0; ob < 12; ++ob) {
    const int o0 = ob * 16;
    float acc[16];
#pragma unroll
    for (int j = 0; j < 16; ++j) acc[j] = s_fib2[o0 + j];
#pragma unroll 4
    for (int c = 0; c < 48; ++c) {
      const float xv = y[c];
      const float4 w0 = *(const float4*)&wT2[c * 192 + o0];
      const float4 w1 = *(const float4*)&wT2[c * 192 + o0 + 4];
      const float4 w2 = *(const float4*)&wT2[c * 192 + o0 + 8];
      const float4 w3 = *(const float4*)&wT2[c * 192 + o0 + 12];
      acc[0] += w0.x * xv; acc[1] += w0.y * xv; acc[2] += w0.z * xv; acc[3] += w0.w * xv;
      acc[4] += w1.x * xv; acc[5] += w1.y * xv; acc[6] += w1.z * xv; acc[7] += w1.w * xv;
      acc[8] += w2.x * xv; acc[9] += w2.y * xv; acc[10] += w2.z * xv; acc[11] += w2.w * xv;
      acc[12] += w3.x * xv; acc[13] += w3.y * xv; acc[14] += w3.z * xv; acc[15] += w3.w * xv;
    }
    F4U u;
    u.u[0] = fpack(acc[0], acc[1]);   u.u[1] = fpack(acc[2], acc[3]);
    u.u[2] = fpack(acc[4], acc[5]);   u.u[3] = fpack(acc[6], acc[7]);
    *(float4*)(rowp + (2 * ob) * 4096) = u.f4;
    u.u[0] = fpack(acc[8], acc[9]);   u.u[1] = fpack(acc[10], acc[11]);
    u.u[2] = fpack(acc[12], acc[13]); u.u[3] = fpack(acc[14], acc[15]);
    *(float4*)(rowp + (2 * ob + 1) * 4096) = u.f4;
  }
}

// ====== k5b: dw + SimpleGate + ffn_out + out_proj [(256,2), r19 verbatim] ===
__global__ __launch_bounds__(256, 2) void k5b(
    const char* __restrict__ region, const float4* __restrict__ s0arr,
    const float* __restrict__ fdww, const float* __restrict__ fdwb,
    const float* __restrict__ fow, const float* __restrict__ fob,
    const float* __restrict__ opw, const float* __restrict__ opb,
    float* __restrict__ out) {
  __shared__ unsigned int halo[12 * HSTRIDE];
  __shared__ __align__(16) float fowT[96 * 48];   // fowT[c1][o] = fow[o][c1]
  __shared__ float s_dww2[1728], s_dwb2[192], s_opw[144], s_fob[48];
  const int tid = threadIdx.x;
  for (int i = tid; i < 4608; i += 256) {
    const int c = i / 48, o = i - c * 48;
    fowT[i] = fow[o * 96 + c];
  }
  for (int i = tid; i < 1728; i += 256) {
    const int P = i / 9, t = i - P * 9;
    const int ch = (P & 1) ? 96 + (P >> 1) : (P >> 1);
    s_dww2[i] = fdww[ch * 9 + t];
  }
  if (tid < 192) {
    const int ch = (tid & 1) ? 96 + (tid >> 1) : (tid >> 1);
    s_dwb2[tid] = fdwb[ch];
  }
  if (tid < 144) s_opw[tid] = opw[tid];
  if (tid < 48) s_fob[tid] = fob[tid];
  const int b = blockIdx.x >> 8;
  const int tile = blockIdx.x & 255;
  const int ty0 = (tile >> 4) << 4, tx0 = (tile & 15) << 4;
  const int py = tid >> 4, px = tid & 15;
  const int hp = (py + 1) * 18 + (px + 1);
  const int gn = ((ty0 + py) << 8) + (tx0 + px);
  const char* regb = region + (size_t)b * REGPB;

  float4 pf[4];
  auto prefetch = [&](int cb) {
#pragma unroll
    for (int r = 0; r < 4; ++r) {
      const int i = tid + (r << 8);
      float4 z = {0.f, 0.f, 0.f, 0.f}; pf[r] = z;
      if (i < 972) {
        const int c4 = i / 324, p = i - c4 * 324;
        const int hy = p / 18, hx = p - hy * 18;
        const int gy = ty0 + hy - 1, gx = tx0 + hx - 1;
        if (((unsigned)gy < 256u) && ((unsigned)gx < 256u))
          pf[r] = *(const float4*)(regb + (size_t)gy * ROWB + (cb + c4) * 4096 + (gx << 4));
      }
    }
  };
  auto commit = [&]() {
#pragma unroll
    for (int r = 0; r < 4; ++r) {
      const int i = tid + (r << 8);
      if (i < 972) {
        const int c4 = i / 324, p = i - c4 * 324;
        F4U u; u.f4 = pf[r];
        const int pb = c4 << 2;
#pragma unroll
        for (int j = 0; j < 4; ++j) halo[(pb + j) * HSTRIDE + p] = u.u[j];
      }
    }
  };

  float facc[48];
#pragma unroll
  for (int o = 0; o < 48; ++o) facc[o] = 0.f;
  prefetch(0);
  for (int s = 0; s < 8; ++s) {
    __syncthreads(); commit(); __syncthreads();
    if (s < 7) prefetch(3 * (s + 1));
    const int offs[9] = {-19, -18, -17, -1, 0, 1, 17, 18, 19};
#pragma unroll
    for (int pp = 0; pp < 12; ++pp) {
      const int P = 24 * s + 2 * pp;
      const float* w0 = &s_dww2[P * 9];
      const float* w1 = w0 + 9;
      const unsigned int* hrow = &halo[pp * HSTRIDE + hp];
      float a = s_dwb2[P], b2 = s_dwb2[P + 1];
#pragma unroll
      for (int t = 0; t < 9; ++t) {
        const float2 f = uh2f(hrow[offs[t]]);
        a += w0[t] * f.x; b2 += w1[t] * f.y;
      }
      const float gate = a * b2;
      const float* fr = &fowT[(12 * s + pp) * 48];
#pragma unroll
      for (int o4 = 0; o4 < 12; ++o4) {
        const float4 m = *(const float4*)&fr[o4 * 4];
        facc[o4 * 4 + 0] += m.x * gate; facc[o4 * 4 + 1] += m.y * gate;
        facc[o4 * 4 + 2] += m.z * gate; facc[o4 * 4 + 3] += m.w * gate;
      }
    }
  }
  const float4 s0v = s0arr[(size_t)b * NPIX + gn];
  float r0 = s0v.x + opb[0];
  float r1 = s0v.y + opb[1];
  float r2 = s0v.z + opb[2];
#pragma unroll
  for (int o = 0; o < 48; ++o) {
    const float f = facc[o] + s_fob[o];
    r0 += s_opw[o] * f; r1 += s_opw[48 + o] * f; r2 += s_opw[96 + o] * f;
  }
  out[((size_t)b * 3 + 0) * NPIX + gn] = r0;
  out[((size_t)b * 3 + 1) * NPIX + gn] = r1;
  out[((size_t)b * 3 + 2) * NPIX + gn] = r2;
}

extern "C" void kernel_launch(void* const* d_in, const int* in_sizes, int n_in,
                              void* d_out, int out_size, void* d_ws, size_t ws_size,
                              hipStream_t stream) {
  const float* x    = (const float*)d_in[0];
  const float* ipw  = (const float*)d_in[1];
  const float* ipb  = (const float*)d_in[2];
  const float* ln1w = (const float*)d_in[3];
  const float* ln1b = (const float*)d_in[4];
  const float* qw   = (const float*)d_in[5];
  const float* qb   = (const float*)d_in[6];
  const float* qdww = (const float*)d_in[7];
  const float* qdwb = (const float*)d_in[8];
  const float* temp = (const float*)d_in[9];
  const float* aow  = (const float*)d_in[10];
  const float* aob  = (const float*)d_in[11];
  const float* ln2w = (const float*)d_in[12];
  const float* ln2b = (const float*)d_in[13];
  const float* fiw  = (const float*)d_in[14];
  const float* fib  = (const float*)d_in[15];
  const float* fdww = (const float*)d_in[16];
  const float* fdwb = (const float*)d_in[17];
  const float* fow  = (const float*)d_in[18];
  const float* fob  = (const float*)d_in[19];
  const float* opw  = (const float*)d_in[20];
  const float* opb  = (const float*)d_in[21];

  const size_t s0Per = (size_t)NPIX * 16;
  int bc = 8;
  while (bc > 1 &&
         (size_t)bc * (REGPB + s0Per) + (5376 + 18432) * 4 > ws_size)
    bc >>= 1;
  char* region = (char*)d_ws;
  float4* s0arr = (float4*)(region + (size_t)bc * REGPB);
  float* red = (float*)((char*)s0arr + (size_t)bc * s0Per);
  float* Mws = red + 5376;
  hipMemsetAsync(red, 0, 5376 * sizeof(float), stream);
  for (int b0 = 0; b0 < 8; b0 += bc) {
    kA8<<<bc * 256, 256, 0, stream>>>(x + (size_t)b0 * 3 * NPIX, ipw, ipb,
                                      ln1w, ln1b, qw, qb, qdww, qdwb,
                                      region, red + b0 * 672);
    k3_attn<<<bc, 256, 0, stream>>>(red + b0 * 672, temp, aow,
                                    Mws + (size_t)b0 * 2304);
    k4a<<<bc * 256, 256, 0, stream>>>(region, s0arr, x + (size_t)b0 * 3 * NPIX,
                                      ipw, ipb, Mws + (size_t)b0 * 2304, aob,
                                      ln2w, ln2b, fiw, fib, opw);
    k5b<<<bc * 256, 256, 0, stream>>>(region, s0arr, fdww, fdwb, fow, fob,
                                      opw, opb,
                                      (float*)d_out + (size_t)b0 * 3 * NPIX);
  }
}